// Round 1
// baseline (6073.884 us; speedup 1.0000x reference)
//
#include <hip/hip_runtime.h>
#include <hip/hip_bf16.h>
#include <math.h>

// Problem constants (B=1)
#define HQ      8
#define QLEN    1024
#define NKEYS   8192
#define NCKEYS  1024
#define DDIM    128

// v0 baseline: one wave (64 threads) per (head, query-row).
// Flash-style online softmax in fp32, two passes (teacher, compressed),
// fused (z - zc)^2 reduction -> atomicAdd into scalar loss.
__global__ __launch_bounds__(64) void attn_mse_kernel(
    const float* __restrict__ Qm, const float* __restrict__ Km,
    const float* __restrict__ Vm, const float* __restrict__ CKm,
    const float* __restrict__ CVm, float* __restrict__ out)
{
    __shared__ float q_lds[DDIM];
    __shared__ float p_lds[64];

    const int gid  = blockIdx.x;     // 0 .. H*Q-1
    const int h    = gid >> 10;      // / QLEN
    const int qr   = gid & 1023;     // % QLEN
    const int lane = threadIdx.x;

    const float* qrow = Qm + ((size_t)h * QLEN + qr) * DDIM;
    // stage q row into LDS (broadcast-read later)
    {
        float2 v = *(const float2*)(qrow + lane * 2);
        *(float2*)(q_lds + lane * 2) = v;
    }
    __syncthreads();

    const float scale = 0.08838834764831845f; // 1/sqrt(128)

    float z0 = 0.f, z1 = 0.f, zc0 = 0.f, zc1 = 0.f;

    for (int pass = 0; pass < 2; ++pass) {
        const float* K = pass ? CKm : Km;
        const float* V = pass ? CVm : Vm;
        const int    n = pass ? NCKEYS : NKEYS;
        const float* Kh = K + (size_t)h * n * DDIM;
        const float* Vh = V + (size_t)h * n * DDIM;

        float m = -1e30f, l = 0.f, a0 = 0.f, a1 = 0.f;

        for (int base = 0; base < n; base += 64) {
            // ---- scores: one key per lane, dot over d=128 ----
            const float4* krow = (const float4*)(Kh + (size_t)(base + lane) * DDIM);
            float s = 0.f;
            #pragma unroll 8
            for (int i = 0; i < 32; ++i) {
                float4 qv = ((const float4*)q_lds)[i];   // LDS broadcast
                float4 kv = krow[i];
                s += qv.x * kv.x + qv.y * kv.y + qv.z * kv.z + qv.w * kv.w;
            }
            s *= scale;

            // ---- online softmax update (stats are scalar per wave) ----
            float mloc = s;
            #pragma unroll
            for (int off = 1; off < 64; off <<= 1)
                mloc = fmaxf(mloc, __shfl_xor(mloc, off));
            float mnew  = fmaxf(m, mloc);
            float p     = __expf(s - mnew);
            float psum  = p;
            #pragma unroll
            for (int off = 1; off < 64; off <<= 1)
                psum += __shfl_xor(psum, off);
            float alpha = __expf(m - mnew);
            l  = l * alpha + psum;
            a0 *= alpha;
            a1 *= alpha;
            m  = mnew;

            // ---- PV: broadcast p via LDS; each lane owns 2 d-dims ----
            p_lds[lane] = p;
            __syncthreads();
            #pragma unroll 8
            for (int j = 0; j < 64; ++j) {
                float  pj = p_lds[j];                     // LDS broadcast
                float2 v2 = *(const float2*)(Vh + (size_t)(base + j) * DDIM + lane * 2);
                a0 += pj * v2.x;
                a1 += pj * v2.y;
            }
            __syncthreads();  // before p_lds is overwritten next chunk
        }

        float inv_l = 1.0f / l;
        if (pass == 0) { z0 = a0 * inv_l; z1 = a1 * inv_l; }
        else           { zc0 = a0 * inv_l; zc1 = a1 * inv_l; }
    }

    // ---- fused MSE contribution ----
    float d0 = z0 - zc0, d1 = z1 - zc1;
    float val = d0 * d0 + d1 * d1;
    #pragma unroll
    for (int off = 1; off < 64; off <<= 1)
        val += __shfl_xor(val, off);
    if (lane == 0)
        atomicAdd(out, val * (1.0f / ((float)HQ * QLEN * DDIM)));
}

extern "C" void kernel_launch(void* const* d_in, const int* in_sizes, int n_in,
                              void* d_out, int out_size, void* d_ws, size_t ws_size,
                              hipStream_t stream) {
    const float* q  = (const float*)d_in[0];
    const float* k  = (const float*)d_in[1];
    const float* v  = (const float*)d_in[2];
    const float* ck = (const float*)d_in[3];
    const float* cv = (const float*)d_in[4];
    float* out = (float*)d_out;

    // d_out is poisoned before every launch; we accumulate into it.
    hipMemsetAsync(out, 0, sizeof(float), stream);

    dim3 grid(HQ * QLEN);
    dim3 block(64);
    attn_mse_kernel<<<grid, block, 0, stream>>>(q, k, v, ck, cv, out);
}

// Round 2
// 571.050 us; speedup vs baseline: 10.6363x; 10.6363x over previous
//
#include <hip/hip_runtime.h>
#include <hip/hip_bf16.h>

#define H_   8
#define Q_   1024
#define N_   8192
#define NC_  1024
#define D_   128
#define KVB  32

typedef __attribute__((ext_vector_type(8))) short          bf16x8;
typedef __attribute__((ext_vector_type(8))) unsigned short u16x8;
typedef __attribute__((ext_vector_type(4))) float          f32x4;

__device__ __forceinline__ unsigned short f2b(float x) {
    __hip_bfloat16 h = __float2bfloat16(x);   // RNE
    unsigned short u;
    __builtin_memcpy(&u, &h, sizeof(u));
    return u;
}

// 2 waves/block, 16 q-rows per wave, KVB=32 keys per iter, both passes fused.
__global__ __launch_bounds__(128) void fused_attn_mse(
    const float* __restrict__ Qm, const float* __restrict__ Km,
    const float* __restrict__ Vm, const float* __restrict__ CKm,
    const float* __restrict__ CVm, float* __restrict__ out)
{
    // K tile: [32 keys][128 d] bf16, XOR-swizzled (byte ^= (row&7)<<4), rows 256B
    __shared__ __align__(16) unsigned short Kl[2][KVB * D_];      // 2 x 8KB
    // V^T tile: [128 d][40 keys(pad)] bf16, row stride 80B (bank spread, 16B aligned)
    __shared__ __align__(16) unsigned short Vt[2][D_ * 40];       // 2 x 10KB
    // P tile per wave: [16 q][32 keys] bf16, byte ^= ((row>>2)&3)<<4
    __shared__ __align__(16) unsigned short Pl[2][16 * KVB];      // 2 x 1KB
    __shared__ float red[2];

    const int tid = threadIdx.x;
    const int w = tid >> 6, l = tid & 63, g = l >> 4, c = l & 15;
    const int h = blockIdx.x >> 5, qt = blockIdx.x & 31;

    // ---- Q fragments (held in registers, scale folded in) ----
    bf16x8 qf[4];
    {
        const float* qrow = Qm + ((size_t)(h * Q_) + qt * 32 + w * 16 + c) * D_;
        const float scale = 0.08838834764831845f;  // 1/sqrt(128)
        #pragma unroll
        for (int dc = 0; dc < 4; ++dc) {
            const float4* p = (const float4*)(qrow + dc * 32 + 8 * g);
            float4 a = p[0], b = p[1];
            u16x8 u;
            u[0] = f2b(a.x * scale); u[1] = f2b(a.y * scale);
            u[2] = f2b(a.z * scale); u[3] = f2b(a.w * scale);
            u[4] = f2b(b.x * scale); u[5] = f2b(b.y * scale);
            u[6] = f2b(b.z * scale); u[7] = f2b(b.w * scale);
            qf[dc] = __builtin_bit_cast(bf16x8, u);
        }
    }

    f32x4 z[8];          // teacher output tile (pass 0 result)
    float sqacc = 0.f;   // per-lane sum of squared diffs

    for (int pass = 0; pass < 2; ++pass) {
        const int   n     = pass ? NC_ : N_;
        const float* Kh   = (pass ? CKm : Km) + (size_t)h * n * D_;
        const float* Vh   = (pass ? CVm : Vm) + (size_t)h * n * D_;
        const int   niter = n / KVB;

        auto stage_load = [&](int n0, float4 (&kr)[4][2], float (&vk)[32]) {
            #pragma unroll
            for (int w4 = 0; w4 < 4; ++w4) {
                int cid = w4 * 128 + tid, row = cid >> 4, c8 = cid & 15;
                const float4* p = (const float4*)(Kh + (size_t)(n0 + row) * D_ + c8 * 8);
                kr[w4][0] = p[0]; kr[w4][1] = p[1];
            }
            #pragma unroll
            for (int k = 0; k < 32; ++k)
                vk[k] = Vh[(size_t)(n0 + k) * D_ + tid];
        };
        auto stage_store = [&](int buf, const float4 (&kr)[4][2], const float (&vk)[32]) {
            char* Kc = (char*)Kl[buf];
            #pragma unroll
            for (int w4 = 0; w4 < 4; ++w4) {
                int cid = w4 * 128 + tid, row = cid >> 4, c8 = cid & 15;
                u16x8 u;
                u[0] = f2b(kr[w4][0].x); u[1] = f2b(kr[w4][0].y);
                u[2] = f2b(kr[w4][0].z); u[3] = f2b(kr[w4][0].w);
                u[4] = f2b(kr[w4][1].x); u[5] = f2b(kr[w4][1].y);
                u[6] = f2b(kr[w4][1].z); u[7] = f2b(kr[w4][1].w);
                *(u16x8*)(Kc + ((row * 256 + c8 * 16) ^ ((row & 7) << 4))) = u;
            }
            char* Vc = (char*)Vt[buf];
            #pragma unroll
            for (int s = 0; s < 4; ++s) {
                u16x8 u;
                #pragma unroll
                for (int i = 0; i < 8; ++i) u[i] = f2b(vk[s * 8 + i]);
                *(u16x8*)(Vc + tid * 80 + s * 16) = u;
            }
        };

        // accumulators / softmax state
        f32x4 o[8];
        #pragma unroll
        for (int dt = 0; dt < 8; ++dt) o[dt] = (f32x4){0.f, 0.f, 0.f, 0.f};
        float m[4], lsum[4];
        #pragma unroll
        for (int j = 0; j < 4; ++j) { m[j] = -1e30f; lsum[j] = 0.f; }

        {   // prologue: stage tile 0 into buf 0
            float4 kr0[4][2]; float vk0[32];
            stage_load(0, kr0, vk0);
            stage_store(0, kr0, vk0);
        }
        __syncthreads();

        for (int it = 0; it < niter; ++it) {
            const int cur  = it & 1;
            const int more = (it + 1 < niter);

            // T14: issue next tile's global loads before compute
            float4 kr[4][2]; float vk[32];
            if (more) stage_load((it + 1) * KVB, kr, vk);

            // ---- S = Q K^T (two 16-key subtiles) ----
            f32x4 s0 = (f32x4){0.f, 0.f, 0.f, 0.f};
            f32x4 s1 = (f32x4){0.f, 0.f, 0.f, 0.f};
            const char* Kc = (const char*)Kl[cur];
            #pragma unroll
            for (int dc = 0; dc < 4; ++dc) {
                bf16x8 k0 = *(const bf16x8*)(Kc + (((c) * 256      + dc * 64 + g * 16) ^ ((c & 7) << 4)));
                bf16x8 k1 = *(const bf16x8*)(Kc + (((16 + c) * 256 + dc * 64 + g * 16) ^ ((c & 7) << 4)));
                s0 = __builtin_amdgcn_mfma_f32_16x16x32_bf16(qf[dc], k0, s0, 0, 0, 0);
                s1 = __builtin_amdgcn_mfma_f32_16x16x32_bf16(qf[dc], k1, s1, 0, 0, 0);
            }

            // ---- online softmax (row r = 4g+j lives in reg j across 16 lanes) ----
            float mx[4];
            #pragma unroll
            for (int j = 0; j < 4; ++j) mx[j] = fmaxf(s0[j], s1[j]);
            #pragma unroll
            for (int off = 1; off < 16; off <<= 1) {
                #pragma unroll
                for (int j = 0; j < 4; ++j)
                    mx[j] = fmaxf(mx[j], __shfl_xor(mx[j], off));
            }
            int chg = 0;
            #pragma unroll
            for (int j = 0; j < 4; ++j) chg |= (mx[j] > m[j]);
            if (__any(chg)) {
                #pragma unroll
                for (int j = 0; j < 4; ++j) {
                    float mn = fmaxf(m[j], mx[j]);
                    float al = __expf(m[j] - mn);
                    m[j] = mn; lsum[j] *= al;
                    #pragma unroll
                    for (int dt = 0; dt < 8; ++dt) o[dt][j] *= al;
                }
            }
            unsigned short pb[8];
            #pragma unroll
            for (int j = 0; j < 4; ++j) {
                float p0 = __expf(s0[j] - m[j]);
                float p1 = __expf(s1[j] - m[j]);
                lsum[j] += p0 + p1;
                pb[j] = f2b(p0); pb[4 + j] = f2b(p1);
            }
            // ---- P -> LDS (D-layout write, A-layout read) ----
            char* Pb = (char*)&Pl[w][0];
            #pragma unroll
            for (int j = 0; j < 4; ++j) {
                *(unsigned short*)(Pb + (((4 * g + j) * 64      + c * 2) ^ (g << 4))) = pb[j];
                *(unsigned short*)(Pb + (((4 * g + j) * 64 + 32 + c * 2) ^ (g << 4))) = pb[4 + j];
            }
            bf16x8 pa = *(const bf16x8*)((const char*)&Pl[w][0] +
                          ((c * 64 + g * 16) ^ (((c >> 2) & 3) << 4)));
            // ---- PV ----
            const char* Vc = (const char*)Vt[cur];
            #pragma unroll
            for (int dt = 0; dt < 8; ++dt) {
                bf16x8 vf = *(const bf16x8*)(Vc + (dt * 16 + c) * 80 + g * 16);
                o[dt] = __builtin_amdgcn_mfma_f32_16x16x32_bf16(pa, vf, o[dt], 0, 0, 0);
            }

            if (more) stage_store(cur ^ 1, kr, vk);
            __syncthreads();
        }

        // ---- finalize pass: reduce row-sums, normalize ----
        #pragma unroll
        for (int off = 1; off < 16; off <<= 1) {
            #pragma unroll
            for (int j = 0; j < 4; ++j) lsum[j] += __shfl_xor(lsum[j], off);
        }
        float inv[4];
        #pragma unroll
        for (int j = 0; j < 4; ++j) inv[j] = 1.0f / lsum[j];

        if (pass == 0) {
            #pragma unroll
            for (int dt = 0; dt < 8; ++dt) {
                #pragma unroll
                for (int j = 0; j < 4; ++j) z[dt][j] = o[dt][j] * inv[j];
            }
        } else {
            #pragma unroll
            for (int dt = 0; dt < 8; ++dt) {
                #pragma unroll
                for (int j = 0; j < 4; ++j) {
                    float d = z[dt][j] - o[dt][j] * inv[j];
                    sqacc += d * d;
                }
            }
        }
        __syncthreads();  // LDS safe for next pass's prologue
    }

    // ---- block MSE reduction -> one atomicAdd ----
    #pragma unroll
    for (int off = 1; off < 64; off <<= 1)
        sqacc += __shfl_xor(sqacc, off);
    if (l == 0) red[w] = sqacc;
    __syncthreads();
    if (tid == 0)
        atomicAdd(out, (red[0] + red[1]) * (1.0f / 1048576.0f));
}

extern "C" void kernel_launch(void* const* d_in, const int* in_sizes, int n_in,
                              void* d_out, int out_size, void* d_ws, size_t ws_size,
                              hipStream_t stream) {
    const float* q  = (const float*)d_in[0];
    const float* k  = (const float*)d_in[1];
    const float* v  = (const float*)d_in[2];
    const float* ck = (const float*)d_in[3];
    const float* cv = (const float*)d_in[4];
    float* out = (float*)d_out;

    hipMemsetAsync(out, 0, sizeof(float), stream);
    fused_attn_mse<<<dim3(H_ * 32), dim3(128), 0, stream>>>(q, k, v, ck, cv, out);
}

// Round 3
// 249.093 us; speedup vs baseline: 24.3840x; 2.2925x over previous
//
#include <hip/hip_runtime.h>
#include <hip/hip_bf16.h>

#define H_   8
#define Q_   1024
#define N_   8192
#define NC_  1024
#define D_   128

typedef __attribute__((ext_vector_type(8))) short          bf16x8;
typedef __attribute__((ext_vector_type(8))) unsigned short u16x8;
typedef __attribute__((ext_vector_type(4))) float          f32x4;

__device__ __forceinline__ unsigned short f2b(float x) {
    __hip_bfloat16 h = __float2bfloat16(x);   // RNE
    unsigned short u;
    __builtin_memcpy(&u, &h, sizeof(u));
    return u;
}

__device__ __forceinline__ void async16(void* lds, const void* gsrc) {
    __builtin_amdgcn_global_load_lds(
        (const __attribute__((address_space(1))) unsigned int*)gsrc,
        (__attribute__((address_space(3))) unsigned int*)lds, 16, 0, 0);
}

// ============================================================================
// Pre-pass: fp32 K/V/CK/CV -> bf16, chunked per 32 keys (16 KB: K 8KB | V^T 8KB),
// with the LDS read-side XOR swizzle pre-baked into the global layout.
//   K slot  (slot<512):  k'=slot>>4, dX=slot&15, dslot=dX^(k'&15)
//   V slot  (slot>=512): s2=slot-512, d=s2>>2, kX=s2&3, kslot=kX^(d&3)
// Chunks: teacher h*256+kc (2048), compressed 2048 + h*32 + kc (256).
// ============================================================================
__global__ __launch_bounds__(256) void convert_kv(
    const float* __restrict__ Km, const float* __restrict__ Vm,
    const float* __restrict__ CKm, const float* __restrict__ CVm,
    unsigned short* __restrict__ ws)
{
    const int b     = blockIdx.x;           // 9216
    const int chunk = b >> 2;               // 0..2303
    const int slot  = (b & 3) * 256 + threadIdx.x;   // 0..1023 (uniform branch/blk)

    const float* Kp; const float* Vp; int h, kc, n;
    if (chunk < 2048) { h = chunk >> 8; kc = chunk & 255; Kp = Km;  Vp = Vm;  n = N_;  }
    else { int c2 = chunk - 2048; h = c2 >> 5; kc = c2 & 31; Kp = CKm; Vp = CVm; n = NC_; }

    const size_t rowbase = ((size_t)h * n + kc * 32) * D_;
    u16x8 o;
    if (slot < 512) {
        int kp = slot >> 4, dX = slot & 15, ds = dX ^ (kp & 15);
        const float* src = Kp + rowbase + (size_t)kp * D_ + ds * 8;
        float4 a = ((const float4*)src)[0], c4 = ((const float4*)src)[1];
        o[0] = f2b(a.x);  o[1] = f2b(a.y);  o[2] = f2b(a.z);  o[3] = f2b(a.w);
        o[4] = f2b(c4.x); o[5] = f2b(c4.y); o[6] = f2b(c4.z); o[7] = f2b(c4.w);
    } else {
        int s2 = slot - 512, d = s2 >> 2, kX = s2 & 3, ks = kX ^ (d & 3);
        const float* src = Vp + rowbase + (size_t)(ks * 8) * D_ + d;
        #pragma unroll
        for (int i = 0; i < 8; ++i) o[i] = f2b(src[i * D_]);
    }
    *(u16x8*)(ws + (size_t)chunk * 8192 + slot * 8) = o;
}

// ============================================================================
// Main: 256 blocks (h,qt via XCD swizzle) x 512 threads = 8 waves.
// Wave w = (gi = w>>1 key-group, wg = w&1 q-half). Block q-tile = 32 rows.
// Group gi: private double-buffered [K 8KB|V 8KB] tile, keys gi*quarter.
// End: 4-way split-K softmax combine via LDS, fused MSE -> one atomicAdd.
// ============================================================================
#define KV_BYTES   131072           // 4 groups x 2 bufs x 16 KB
#define P_OFF      131072           // 8 waves x 1 KB
#define CM_OFF     139264
#define CL_OFF     139776
#define RED_OFF    140288
#define SMEM_BYTES 140320

__global__ __launch_bounds__(512, 2) void attn_mse_main(
    const float* __restrict__ Qm, const unsigned short* __restrict__ ws,
    float* __restrict__ out)
{
    __shared__ __align__(16) char smem[SMEM_BYTES];

    const int tid = threadIdx.x;
    const int w   = tid >> 6;
    const int gi  = w >> 1, wg = w & 1;
    const int ln  = tid & 63, g = ln >> 4, c = ln & 15;

    const int bid = blockIdx.x;
    const int swz = (bid & 7) * 32 + (bid >> 3);   // head-per-XCD
    const int h = swz >> 5, qt = swz & 31;

    char*  myKV = smem + gi * 32768;
    char*  Pb   = smem + P_OFF + w * 1024;
    float* cm   = (float*)(smem + CM_OFF);
    float* cl   = (float*)(smem + CL_OFF);
    float* red  = (float*)(smem + RED_OFF);

    // ---- Q fragments (scale folded) ----
    bf16x8 qf[4];
    {
        const float* qrow = Qm + ((size_t)(h * Q_) + qt * 32 + wg * 16 + c) * D_;
        const float scale = 0.08838834764831845f;  // 1/sqrt(128)
        #pragma unroll
        for (int dc = 0; dc < 4; ++dc) {
            const float4* p = (const float4*)(qrow + dc * 32 + 8 * g);
            float4 a = p[0], b = p[1];
            u16x8 u;
            u[0] = f2b(a.x * scale); u[1] = f2b(a.y * scale);
            u[2] = f2b(a.z * scale); u[3] = f2b(a.w * scale);
            u[4] = f2b(b.x * scale); u[5] = f2b(b.y * scale);
            u[6] = f2b(b.z * scale); u[7] = f2b(b.w * scale);
            qf[dc] = __builtin_bit_cast(bf16x8, u);
        }
    }

    auto stage = [&](const unsigned short* chunk_src, int buf) {
        const char* s = (const char*)chunk_src + wg * 8192 + ln * 16;
        char* d = myKV + buf * 16384 + wg * 8192;
        #pragma unroll
        for (int i = 0; i < 8; ++i)
            async16(d + i * 1024, s + i * 1024);
    };

    auto compute = [&](int cur, f32x4 (&o)[8], float (&m)[4], float (&ls)[4]) {
        const char* Kc = myKV + cur * 16384;
        const char* Vc = Kc + 8192;
        f32x4 s0 = (f32x4){0.f,0.f,0.f,0.f};
        f32x4 s1 = (f32x4){0.f,0.f,0.f,0.f};
        #pragma unroll
        for (int dc = 0; dc < 4; ++dc) {
            bf16x8 k0 = *(const bf16x8*)(Kc + c * 256        + (((dc*4+g) ^ c) << 4));
            bf16x8 k1 = *(const bf16x8*)(Kc + (16 + c) * 256 + (((dc*4+g) ^ c) << 4));
            s0 = __builtin_amdgcn_mfma_f32_16x16x32_bf16(qf[dc], k0, s0, 0, 0, 0);
            s1 = __builtin_amdgcn_mfma_f32_16x16x32_bf16(qf[dc], k1, s1, 0, 0, 0);
        }
        float mx[4];
        #pragma unroll
        for (int j = 0; j < 4; ++j) mx[j] = fmaxf(s0[j], s1[j]);
        #pragma unroll
        for (int off = 1; off < 16; off <<= 1) {
            #pragma unroll
            for (int j = 0; j < 4; ++j) mx[j] = fmaxf(mx[j], __shfl_xor(mx[j], off));
        }
        int chg = 0;
        #pragma unroll
        for (int j = 0; j < 4; ++j) chg |= (mx[j] > m[j]);
        if (__any(chg)) {
            #pragma unroll
            for (int j = 0; j < 4; ++j) {
                float mn = fmaxf(m[j], mx[j]);
                float al = __expf(m[j] - mn);
                m[j] = mn; ls[j] *= al;
                #pragma unroll
                for (int dt = 0; dt < 8; ++dt) o[dt][j] *= al;
            }
        }
        unsigned short pb[8];
        #pragma unroll
        for (int j = 0; j < 4; ++j) {
            float p0 = __expf(s0[j] - m[j]);
            float p1 = __expf(s1[j] - m[j]);
            ls[j] += p0 + p1;
            pb[j] = f2b(p0); pb[4 + j] = f2b(p1);
        }
        #pragma unroll
        for (int j = 0; j < 4; ++j) {
            int row = 4 * g + j;
            *(unsigned short*)(Pb + row * 64 + ((((c >> 3))     ^ g) << 4) + (c & 7) * 2) = pb[j];
            *(unsigned short*)(Pb + row * 64 + (((2 + (c >> 3)) ^ g) << 4) + (c & 7) * 2) = pb[4 + j];
        }
        bf16x8 pa = *(const bf16x8*)(Pb + c * 64 + ((g ^ ((c >> 2) & 3)) << 4));
        #pragma unroll
        for (int dt = 0; dt < 8; ++dt) {
            bf16x8 vf = *(const bf16x8*)(Vc + (dt * 16 + c) * 64 + ((g ^ (c & 3)) << 4));
            o[dt] = __builtin_amdgcn_mfma_f32_16x16x32_bf16(pa, vf, o[dt], 0, 0, 0);
        }
    };

    auto run_pass = [&](const unsigned short* pbase, int niter,
                        f32x4 (&o)[8], float (&m)[4], float (&ls)[4]) {
        #pragma unroll
        for (int dt = 0; dt < 8; ++dt) o[dt] = (f32x4){0.f,0.f,0.f,0.f};
        #pragma unroll
        for (int j = 0; j < 4; ++j) { m[j] = -1e30f; ls[j] = 0.f; }
        stage(pbase, 0);
        __syncthreads();
        for (int it = 0; it < niter; ++it) {
            int cur = it & 1;
            if (it + 1 < niter) stage(pbase + (size_t)(it + 1) * 8192, cur ^ 1);
            compute(cur, o, m, ls);
            __syncthreads();   // drains vmcnt -> next buf ready; pair stays lockstep
        }
        #pragma unroll
        for (int off = 1; off < 16; off <<= 1) {
            #pragma unroll
            for (int j = 0; j < 4; ++j) ls[j] += __shfl_xor(ls[j], off);
        }
    };

    // combine 4 key-group partials (raw o, l) -> z for (wg rows, gi d-quarter)
    auto combine = [&](f32x4 (&o)[8], float (&m)[4], float (&ls)[4], float (&zr)[8]) {
        __syncthreads();                       // KV LDS reusable / prev co readers done
        float* co = (float*)smem;              // [8 slots][16 rows][132]
        #pragma unroll
        for (int dt = 0; dt < 8; ++dt) {
            #pragma unroll
            for (int j = 0; j < 4; ++j)
                co[(w * 16 + 4 * g + j) * 132 + dt * 16 + c] = o[dt][j];
        }
        if (c == 0) {
            #pragma unroll
            for (int j = 0; j < 4; ++j) {
                cm[w * 16 + 4 * g + j] = m[j];
                cl[w * 16 + 4 * g + j] = ls[j];
            }
        }
        __syncthreads();
        const int row = ln >> 2;
        const int d0  = gi * 32 + (ln & 3) * 8;
        float mg[4], M = -1e30f;
        #pragma unroll
        for (int g2 = 0; g2 < 4; ++g2) {
            mg[g2] = cm[(g2 * 2 + wg) * 16 + row];
            M = fmaxf(M, mg[g2]);
        }
        float L = 0.f, acc[8];
        #pragma unroll
        for (int i = 0; i < 8; ++i) acc[i] = 0.f;
        #pragma unroll
        for (int g2 = 0; g2 < 4; ++g2) {
            float wt = __expf(mg[g2] - M);
            L += cl[(g2 * 2 + wg) * 16 + row] * wt;
            const float* p = co + ((g2 * 2 + wg) * 16 + row) * 132 + d0;
            #pragma unroll
            for (int i = 0; i < 8; ++i) acc[i] += p[i] * wt;
        }
        float invL = 1.0f / L;
        #pragma unroll
        for (int i = 0; i < 8; ++i) zr[i] = acc[i] * invL;
    };

    f32x4 ot[8], oc[8];
    float mt[4], lt[4], mc[4], lcs[4];
    run_pass(ws + (size_t)(h * 256 + gi * 64) * 8192, 64, ot, mt, lt);
    run_pass(ws + (size_t)(2048 + h * 32 + gi * 8) * 8192, 8, oc, mc, lcs);

    float zt[8], zc[8];
    combine(ot, mt, lt, zt);
    combine(oc, mc, lcs, zc);   // its leading barrier orders co overwrite

    float sq = 0.f;
    #pragma unroll
    for (int i = 0; i < 8; ++i) { float d = zt[i] - zc[i]; sq += d * d; }
    #pragma unroll
    for (int off = 1; off < 64; off <<= 1) sq += __shfl_xor(sq, off);
    if (ln == 0) red[w] = sq;
    __syncthreads();
    if (tid == 0) {
        float s = 0.f;
        #pragma unroll
        for (int i = 0; i < 8; ++i) s += red[i];
        atomicAdd(out, s * (1.0f / 1048576.0f));
    }
}

// ============================================================================
// Fallback (R2 kernel): used only if ws_size is too small for the bf16 cache.
// ============================================================================
__global__ __launch_bounds__(128) void fused_attn_mse(
    const float* __restrict__ Qm, const float* __restrict__ Km,
    const float* __restrict__ Vm, const float* __restrict__ CKm,
    const float* __restrict__ CVm, float* __restrict__ out)
{
    __shared__ __align__(16) unsigned short Kl[2][32 * D_];
    __shared__ __align__(16) unsigned short Vt[2][D_ * 40];
    __shared__ __align__(16) unsigned short Pl[2][16 * 32];
    __shared__ float red[2];

    const int tid = threadIdx.x;
    const int w = tid >> 6, l = tid & 63, g = l >> 4, c = l & 15;
    const int h = blockIdx.x >> 5, qt = blockIdx.x & 31;

    bf16x8 qf[4];
    {
        const float* qrow = Qm + ((size_t)(h * Q_) + qt * 32 + w * 16 + c) * D_;
        const float scale = 0.08838834764831845f;
        #pragma unroll
        for (int dc = 0; dc < 4; ++dc) {
            const float4* p = (const float4*)(qrow + dc * 32 + 8 * g);
            float4 a = p[0], b = p[1];
            u16x8 u;
            u[0] = f2b(a.x * scale); u[1] = f2b(a.y * scale);
            u[2] = f2b(a.z * scale); u[3] = f2b(a.w * scale);
            u[4] = f2b(b.x * scale); u[5] = f2b(b.y * scale);
            u[6] = f2b(b.z * scale); u[7] = f2b(b.w * scale);
            qf[dc] = __builtin_bit_cast(bf16x8, u);
        }
    }

    f32x4 z[8];
    float sqacc = 0.f;

    for (int pass = 0; pass < 2; ++pass) {
        const int    n  = pass ? NC_ : N_;
        const float* Kh = (pass ? CKm : Km) + (size_t)h * n * D_;
        const float* Vh = (pass ? CVm : Vm) + (size_t)h * n * D_;
        const int niter = n / 32;

        auto stage_load = [&](int n0, float4 (&kr)[4][2], float (&vk)[32]) {
            #pragma unroll
            for (int w4 = 0; w4 < 4; ++w4) {
                int cid = w4 * 128 + tid, row = cid >> 4, c8 = cid & 15;
                const float4* p = (const float4*)(Kh + (size_t)(n0 + row) * D_ + c8 * 8);
                kr[w4][0] = p[0]; kr[w4][1] = p[1];
            }
            #pragma unroll
            for (int k = 0; k < 32; ++k) vk[k] = Vh[(size_t)(n0 + k) * D_ + tid];
        };
        auto stage_store = [&](int buf, const float4 (&kr)[4][2], const float (&vk)[32]) {
            char* Kc = (char*)Kl[buf];
            #pragma unroll
            for (int w4 = 0; w4 < 4; ++w4) {
                int cid = w4 * 128 + tid, row = cid >> 4, c8 = cid & 15;
                u16x8 u;
                u[0] = f2b(kr[w4][0].x); u[1] = f2b(kr[w4][0].y);
                u[2] = f2b(kr[w4][0].z); u[3] = f2b(kr[w4][0].w);
                u[4] = f2b(kr[w4][1].x); u[5] = f2b(kr[w4][1].y);
                u[6] = f2b(kr[w4][1].z); u[7] = f2b(kr[w4][1].w);
                *(u16x8*)(Kc + ((row * 256 + c8 * 16) ^ ((row & 7) << 4))) = u;
            }
            char* Vc = (char*)Vt[buf];
            #pragma unroll
            for (int s = 0; s < 4; ++s) {
                u16x8 u;
                #pragma unroll
                for (int i = 0; i < 8; ++i) u[i] = f2b(vk[s * 8 + i]);
                *(u16x8*)(Vc + tid * 80 + s * 16) = u;
            }
        };

        f32x4 o[8];
        #pragma unroll
        for (int dt = 0; dt < 8; ++dt) o[dt] = (f32x4){0.f,0.f,0.f,0.f};
        float m[4], lsum[4];
        #pragma unroll
        for (int j = 0; j < 4; ++j) { m[j] = -1e30f; lsum[j] = 0.f; }

        {
            float4 kr0[4][2]; float vk0[32];
            stage_load(0, kr0, vk0);
            stage_store(0, kr0, vk0);
        }
        __syncthreads();

        for (int it = 0; it < niter; ++it) {
            const int cur  = it & 1;
            const int more = (it + 1 < niter);
            float4 kr[4][2]; float vk[32];
            if (more) stage_load((it + 1) * 32, kr, vk);

            f32x4 s0 = (f32x4){0.f,0.f,0.f,0.f};
            f32x4 s1 = (f32x4){0.f,0.f,0.f,0.f};
            const char* Kc = (const char*)Kl[cur];
            #pragma unroll
            for (int dc = 0; dc < 4; ++dc) {
                bf16x8 k0 = *(const bf16x8*)(Kc + (((c) * 256      + dc * 64 + g * 16) ^ ((c & 7) << 4)));
                bf16x8 k1 = *(const bf16x8*)(Kc + (((16 + c) * 256 + dc * 64 + g * 16) ^ ((c & 7) << 4)));
                s0 = __builtin_amdgcn_mfma_f32_16x16x32_bf16(qf[dc], k0, s0, 0, 0, 0);
                s1 = __builtin_amdgcn_mfma_f32_16x16x32_bf16(qf[dc], k1, s1, 0, 0, 0);
            }
            float mx[4];
            #pragma unroll
            for (int j = 0; j < 4; ++j) mx[j] = fmaxf(s0[j], s1[j]);
            #pragma unroll
            for (int off = 1; off < 16; off <<= 1) {
                #pragma unroll
                for (int j = 0; j < 4; ++j) mx[j] = fmaxf(mx[j], __shfl_xor(mx[j], off));
            }
            int chg = 0;
            #pragma unroll
            for (int j = 0; j < 4; ++j) chg |= (mx[j] > m[j]);
            if (__any(chg)) {
                #pragma unroll
                for (int j = 0; j < 4; ++j) {
                    float mn = fmaxf(m[j], mx[j]);
                    float al = __expf(m[j] - mn);
                    m[j] = mn; lsum[j] *= al;
                    #pragma unroll
                    for (int dt = 0; dt < 8; ++dt) o[dt][j] *= al;
                }
            }
            unsigned short pb[8];
            #pragma unroll
            for (int j = 0; j < 4; ++j) {
                float p0 = __expf(s0[j] - m[j]);
                float p1 = __expf(s1[j] - m[j]);
                lsum[j] += p0 + p1;
                pb[j] = f2b(p0); pb[4 + j] = f2b(p1);
            }
            char* Pb = (char*)&Pl[w][0];
            #pragma unroll
            for (int j = 0; j < 4; ++j) {
                *(unsigned short*)(Pb + (((4 * g + j) * 64      + c * 2) ^ (g << 4))) = pb[j];
                *(unsigned short*)(Pb + (((4 * g + j) * 64 + 32 + c * 2) ^ (g << 4))) = pb[4 + j];
            }
            bf16x8 pa = *(const bf16x8*)((const char*)&Pl[w][0] +
                          ((c * 64 + g * 16) ^ (((c >> 2) & 3) << 4)));
            const char* Vc = (const char*)Vt[cur];
            #pragma unroll
            for (int dt = 0; dt < 8; ++dt) {
                bf16x8 vf = *(const bf16x8*)(Vc + (dt * 16 + c) * 80 + g * 16);
                o[dt] = __builtin_amdgcn_mfma_f32_16x16x32_bf16(pa, vf, o[dt], 0, 0, 0);
            }
            if (more) stage_store(cur ^ 1, kr, vk);
            __syncthreads();
        }

        #pragma unroll
        for (int off = 1; off < 16; off <<= 1) {
            #pragma unroll
            for (int j = 0; j < 4; ++j) lsum[j] += __shfl_xor(lsum[j], off);
        }
        float inv[4];
        #pragma unroll
        for (int j = 0; j < 4; ++j) inv[j] = 1.0f / lsum[j];

        if (pass == 0) {
            #pragma unroll
            for (int dt = 0; dt < 8; ++dt)
                #pragma unroll
                for (int j = 0; j < 4; ++j) z[dt][j] = o[dt][j] * inv[j];
        } else {
            #pragma unroll
            for (int dt = 0; dt < 8; ++dt)
                #pragma unroll
                for (int j = 0; j < 4; ++j) {
                    float d = z[dt][j] - o[dt][j] * inv[j];
                    sqacc += d * d;
                }
        }
        __syncthreads();
    }

    #pragma unroll
    for (int off = 1; off < 64; off <<= 1) sqacc += __shfl_xor(sqacc, off);
    if (l == 0) red[w] = sqacc;
    __syncthreads();
    if (tid == 0) atomicAdd(out, (red[0] + red[1]) * (1.0f / 1048576.0f));
}

extern "C" void kernel_launch(void* const* d_in, const int* in_sizes, int n_in,
                              void* d_out, int out_size, void* d_ws, size_t ws_size,
                              hipStream_t stream) {
    const float* q  = (const float*)d_in[0];
    const float* k  = (const float*)d_in[1];
    const float* v  = (const float*)d_in[2];
    const float* ck = (const float*)d_in[3];
    const float* cv = (const float*)d_in[4];
    float* out = (float*)d_out;

    hipMemsetAsync(out, 0, sizeof(float), stream);

    const size_t need = (size_t)2304 * 16384;   // 37.75 MB bf16 cache
    if (ws_size >= need) {
        unsigned short* ws = (unsigned short*)d_ws;
        convert_kv<<<dim3(9216), dim3(256), 0, stream>>>(k, v, ck, cv, ws);
        attn_mse_main<<<dim3(256), dim3(512), 0, stream>>>(q, ws, out);
    } else {
        fused_attn_mse<<<dim3(256), dim3(128), 0, stream>>>(q, k, v, ck, cv, out);
    }
}

// Round 4
// 210.250 us; speedup vs baseline: 28.8889x; 1.1848x over previous
//
#include <hip/hip_runtime.h>
#include <hip/hip_bf16.h>

#define H_   8
#define Q_   1024
#define N_   8192
#define NC_  1024
#define D_   128

// ---- converted-KV chunk geometry (64 keys per chunk) ----
#define KSTR  272                      // K row stride: 16 real 16B slots + 1 pad (bank spread)
#define VOFF  17408                    // 64*KSTR
#define VSTR  144                      // V^T row stride: 8 real slots + 1 pad
#define CHB   35840                    // VOFF + 128*VSTR
#define NCHT  1024                     // teacher chunks: 8h * 128
#define NCHC  128                      // compressed chunks: 8h * 16
#define O_OFF   ((size_t)(NCHT + NCHC) * CHB)            // 41,287,680
#define ML_OFF  (O_OFF + (size_t)131072 * 256)           // + o partials (bf16) 33,554,432
#define WS_NEED (ML_OFF + (size_t)131072 * 8)            // + m,l f32  -> 75,890,688

typedef __attribute__((ext_vector_type(8))) short          bf16x8;
typedef __attribute__((ext_vector_type(8))) unsigned short u16x8;
typedef __attribute__((ext_vector_type(4))) float          f32x4;

__device__ __forceinline__ unsigned short f2b(float x) {
    __hip_bfloat16 h = __float2bfloat16(x);   // RNE
    unsigned short u;
    __builtin_memcpy(&u, &h, sizeof(u));
    return u;
}
__device__ __forceinline__ float b2f(unsigned short u) {
    unsigned int x = ((unsigned int)u) << 16;
    float f;
    __builtin_memcpy(&f, &x, sizeof(f));
    return f;
}
__device__ __forceinline__ void async16(void* lds, const void* gsrc) {
    __builtin_amdgcn_global_load_lds(
        (const __attribute__((address_space(1))) unsigned int*)gsrc,
        (__attribute__((address_space(3))) unsigned int*)lds, 16, 0, 0);
}

// ============================================================================
// Convert: fp32 K/V -> bf16 chunks with read-side swizzle pre-baked.
// K slot sl of row r holds d8 = sl ^ (r&15); V^T slot sl of row d' holds
// key-octet k8 = sl ^ (d'&7). V transposed through LDS for coalescing.
// ============================================================================
__global__ __launch_bounds__(256) void convert_kv(
    const float* __restrict__ Km, const float* __restrict__ Vm,
    const float* __restrict__ CKm, const float* __restrict__ CVm,
    char* __restrict__ ws)
{
    __shared__ float vl[64 * 129];     // V tile fp32, padded stride
    const int cid = blockIdx.x;        // 0..1151
    const int tid = threadIdx.x;

    const float* Kp; const float* Vp; int h, kc, n;
    if (cid < NCHT) { h = cid >> 7; kc = cid & 127; Kp = Km; Vp = Vm; n = N_; }
    else { int c2 = cid - NCHT; h = c2 >> 4; kc = c2 & 15; Kp = CKm; Vp = CVm; n = NC_; }
    const size_t base = ((size_t)h * n + (size_t)kc * 64) * D_;

    // phase 1: V[64][128] fp32 -> LDS (coalesced)
    const float4* Vg = (const float4*)(Vp + base);
    #pragma unroll
    for (int s = 0; s < 8; ++s) {
        int fi = s * 256 + tid;                 // 0..2047
        int key = fi >> 5, dp = (fi & 31) * 4;
        float4 v = Vg[fi];
        float* d = vl + key * 129 + dp;
        d[0] = v.x; d[1] = v.y; d[2] = v.z; d[3] = v.w;
    }
    __syncthreads();

    char* cb = ws + (size_t)cid * CHB;

    // phase 2: K slots (64 rows x 17 slots; slot 16 is pad, skipped)
    for (int s = tid; s < 1088; s += 256) {
        int r = s / 17, sl = s - r * 17;
        if (sl < 16) {
            int d8 = sl ^ (r & 15);
            const float4* src = (const float4*)(Kp + base + (size_t)r * D_ + d8 * 8);
            float4 a = src[0], b = src[1];
            u16x8 u;
            u[0] = f2b(a.x); u[1] = f2b(a.y); u[2] = f2b(a.z); u[3] = f2b(a.w);
            u[4] = f2b(b.x); u[5] = f2b(b.y); u[6] = f2b(b.z); u[7] = f2b(b.w);
            *(u16x8*)(cb + r * KSTR + sl * 16) = u;
        }
    }
    // phase 3: V^T slots (128 rows x 9 slots; slot 8 is pad)
    for (int s = tid; s < 1152; s += 256) {
        int r = s / 9, sl = s - r * 9;          // r = d'
        if (sl < 8) {
            int k8 = sl ^ (r & 7);
            const float* col = vl + (k8 * 8) * 129 + r;
            u16x8 u;
            #pragma unroll
            for (int i = 0; i < 8; ++i) u[i] = f2b(col[i * 129]);
            *(u16x8*)(cb + VOFF + r * VSTR + sl * 16) = u;
        }
    }
}

// ============================================================================
// Attention partials: 256 blocks = 8h x 4qt x 8 kv-chunks (XCD-swizzled so a
// head's blocks share an XCD L2). 8 waves x 32 q-rows; KVB=64 double-buffered;
// K/V tile shared by the whole block. Writes (o bf16, m/l f32) partials.
// ============================================================================
__global__ __launch_bounds__(512, 2) void attn_partial(
    const float* __restrict__ Qm, char* __restrict__ ws)
{
    __shared__ __align__(16) char kvbuf[2][CHB];       // 71,680
    __shared__ __align__(16) char pbuf[8][32 * VSTR];  // 36,864 (P per wave)

    const int tid = threadIdx.x;
    const int wq = tid >> 6, ln = tid & 63, g = ln >> 4, c = ln & 15;

    const int bid = blockIdx.x;
    const int xcd = bid & 7, ii = bid >> 3;
    const int pair = xcd * 8 + (ii >> 2), qt = ii & 3;
    const int h = pair >> 3, gch = pair & 7;           // h == xcd: head-per-XCD

    // ---- Q fragments (scale folded), rows qt*256 + wq*32 + rt*16 + c ----
    bf16x8 qf[2][4];
    {
        const float scale = 0.08838834764831845f;      // 1/sqrt(128)
        #pragma unroll
        for (int rt = 0; rt < 2; ++rt) {
            const float* qrow = Qm + ((size_t)h * Q_ + qt * 256 + wq * 32 + rt * 16 + c) * D_;
            #pragma unroll
            for (int dc = 0; dc < 4; ++dc) {
                const float4* p = (const float4*)(qrow + dc * 32 + g * 8);
                float4 a = p[0], b = p[1];
                u16x8 u;
                u[0] = f2b(a.x * scale); u[1] = f2b(a.y * scale);
                u[2] = f2b(a.z * scale); u[3] = f2b(a.w * scale);
                u[4] = f2b(b.x * scale); u[5] = f2b(b.y * scale);
                u[6] = f2b(b.z * scale); u[7] = f2b(b.w * scale);
                qf[rt][dc] = __builtin_bit_cast(bf16x8, u);
            }
        }
    }

    auto stage = [&](size_t cid, int buf) {            // 2240 16B slots, linear
        const char* s = ws + cid * CHB;
        char* d = kvbuf[buf];
        #pragma unroll
        for (int k = 0; k < 4; ++k)
            async16(d + (k * 512 + tid) * 16, s + (size_t)(k * 512 + tid) * 16);
        if (tid < 192) async16(d + (2048 + tid) * 16, s + (size_t)(2048 + tid) * 16);
    };

    f32x4 o[2][8];
    float m[2][4], l[2][4];

    auto compute = [&](int cur) {
        const char* Kc = kvbuf[cur];
        const char* Vc = kvbuf[cur] + VOFF;
        // ---- S = Q K^T : 32 MFMA, 16 K-frag reads ----
        f32x4 s[2][4];
        #pragma unroll
        for (int rt = 0; rt < 2; ++rt)
            #pragma unroll
            for (int kt = 0; kt < 4; ++kt) s[rt][kt] = (f32x4){0.f, 0.f, 0.f, 0.f};
        #pragma unroll
        for (int dc = 0; dc < 4; ++dc) {
            #pragma unroll
            for (int kt = 0; kt < 4; ++kt) {
                bf16x8 kf = *(const bf16x8*)(Kc + (kt * 16 + c) * KSTR + (((dc * 4 + g) ^ c) << 4));
                s[0][kt] = __builtin_amdgcn_mfma_f32_16x16x32_bf16(qf[0][dc], kf, s[0][kt], 0, 0, 0);
                s[1][kt] = __builtin_amdgcn_mfma_f32_16x16x32_bf16(qf[1][dc], kf, s[1][kt], 0, 0, 0);
            }
        }
        // ---- online softmax (row = rt*16 + 4g + j; its 16 lanes share g) ----
        float mx[2][4];
        #pragma unroll
        for (int rt = 0; rt < 2; ++rt)
            #pragma unroll
            for (int j = 0; j < 4; ++j)
                mx[rt][j] = fmaxf(fmaxf(s[rt][0][j], s[rt][1][j]), fmaxf(s[rt][2][j], s[rt][3][j]));
        #pragma unroll
        for (int off = 1; off < 16; off <<= 1)
            #pragma unroll
            for (int rt = 0; rt < 2; ++rt)
                #pragma unroll
                for (int j = 0; j < 4; ++j)
                    mx[rt][j] = fmaxf(mx[rt][j], __shfl_xor(mx[rt][j], off));
        int chg = 0;
        #pragma unroll
        for (int rt = 0; rt < 2; ++rt)
            #pragma unroll
            for (int j = 0; j < 4; ++j) chg |= (mx[rt][j] > m[rt][j]);
        if (__any(chg)) {
            #pragma unroll
            for (int rt = 0; rt < 2; ++rt)
                #pragma unroll
                for (int j = 0; j < 4; ++j) {
                    float mn = fmaxf(m[rt][j], mx[rt][j]);
                    float al = __expf(m[rt][j] - mn);
                    m[rt][j] = mn; l[rt][j] *= al;
                    #pragma unroll
                    for (int dt = 0; dt < 8; ++dt) o[rt][dt][j] *= al;
                }
        }
        // ---- P = exp(S - m) -> LDS (slot = (key>>3) ^ ((row>>2)&7)) ----
        char* Pb = pbuf[wq];
        #pragma unroll
        for (int rt = 0; rt < 2; ++rt)
            #pragma unroll
            for (int kt = 0; kt < 4; ++kt)
                #pragma unroll
                for (int j = 0; j < 4; ++j) {
                    float p = __expf(s[rt][kt][j] - m[rt][j]);
                    l[rt][j] += p;
                    int row = rt * 16 + 4 * g + j;
                    int slot = (kt * 2 + (c >> 3)) ^ ((rt * 4 + g) & 7);
                    *(unsigned short*)(Pb + row * VSTR + slot * 16 + (c & 7) * 2) = f2b(p);
                }
        // ---- PV : 32 MFMA, 4 P-frag + 16 V-frag reads ----
        bf16x8 pa[2][2];
        #pragma unroll
        for (int rt = 0; rt < 2; ++rt)
            #pragma unroll
            for (int kb = 0; kb < 2; ++kb)
                pa[rt][kb] = *(const bf16x8*)(Pb + (rt * 16 + c) * VSTR +
                                 (((kb * 4 + g) ^ ((rt * 4 + (c >> 2)) & 7)) << 4));
        #pragma unroll
        for (int dt = 0; dt < 8; ++dt) {
            const char* vrow = Vc + (dt * 16 + c) * VSTR;
            bf16x8 v0 = *(const bf16x8*)(vrow + ((g ^ (c & 7)) << 4));
            o[0][dt] = __builtin_amdgcn_mfma_f32_16x16x32_bf16(pa[0][0], v0, o[0][dt], 0, 0, 0);
            o[1][dt] = __builtin_amdgcn_mfma_f32_16x16x32_bf16(pa[1][0], v0, o[1][dt], 0, 0, 0);
            bf16x8 v1 = *(const bf16x8*)(vrow + (((4 + g) ^ (c & 7)) << 4));
            o[0][dt] = __builtin_amdgcn_mfma_f32_16x16x32_bf16(pa[0][1], v1, o[0][dt], 0, 0, 0);
            o[1][dt] = __builtin_amdgcn_mfma_f32_16x16x32_bf16(pa[1][1], v1, o[1][dt], 0, 0, 0);
        }
    };

    auto run_pass = [&](size_t cbase, int niter) {
        #pragma unroll
        for (int rt = 0; rt < 2; ++rt) {
            #pragma unroll
            for (int dt = 0; dt < 8; ++dt) o[rt][dt] = (f32x4){0.f, 0.f, 0.f, 0.f};
            #pragma unroll
            for (int j = 0; j < 4; ++j) { m[rt][j] = -1e30f; l[rt][j] = 0.f; }
        }
        stage(cbase, 0);
        __syncthreads();
        for (int it = 0; it < niter; ++it) {
            int cur = it & 1;
            if (it + 1 < niter) stage(cbase + it + 1, cur ^ 1);
            compute(cur);
            __syncthreads();      // drains vmcnt: next buffer is ready
        }
        // reduce row-sums across the 16 lanes sharing each row
        #pragma unroll
        for (int off = 1; off < 16; off <<= 1)
            #pragma unroll
            for (int rt = 0; rt < 2; ++rt)
                #pragma unroll
                for (int j = 0; j < 4; ++j) l[rt][j] += __shfl_xor(l[rt][j], off);
    };

    auto store_partials = [&](int a) {
        unsigned short* oP = (unsigned short*)(ws + O_OFF);
        float2* mlP = (float2*)(ws + ML_OFF);
        #pragma unroll
        for (int rt = 0; rt < 2; ++rt)
            #pragma unroll
            for (int j = 0; j < 4; ++j) {
                int row_glob = h * 1024 + qt * 256 + wq * 32 + rt * 16 + 4 * g + j;
                size_t rec = ((size_t)row_glob * 2 + a) * 8 + gch;
                unsigned short* dst = oP + rec * 128 + c;
                #pragma unroll
                for (int dt = 0; dt < 8; ++dt) dst[dt * 16] = f2b(o[rt][dt][j]);
                if (c == 0) mlP[rec] = make_float2(m[rt][j], l[rt][j]);
            }
    };

    run_pass((size_t)h * 128 + gch * 16, 16);          // teacher: 1024 keys
    store_partials(0);
    run_pass((size_t)NCHT + h * 16 + gch * 2, 2);      // compressed: 128 keys
    store_partials(1);
}

// ============================================================================
// Combine split-K partials (global softmax) for both attentions + fused MSE.
// ============================================================================
__global__ __launch_bounds__(256) void combine_mse(
    const char* __restrict__ ws, float* __restrict__ out)
{
    __shared__ float red[4];
    const int tid = threadIdx.x;
    const int row = blockIdx.x * 32 + (tid >> 3);      // 0..8191
    const int p   = tid & 7;                           // 16-d slice
    const unsigned short* oP = (const unsigned short*)(ws + O_OFF);
    const float2* mlP = (const float2*)(ws + ML_OFF);

    float z[2][16];
    #pragma unroll
    for (int a = 0; a < 2; ++a) {
        size_t rec0 = ((size_t)row * 2 + a) * 8;
        float mg[8], lg[8], M = -1e30f;
        #pragma unroll
        for (int g = 0; g < 8; ++g) {
            float2 t = mlP[rec0 + g];
            mg[g] = t.x; lg[g] = t.y;
            M = fmaxf(M, mg[g]);
        }
        float L = 0.f, acc[16];
        #pragma unroll
        for (int i = 0; i < 16; ++i) acc[i] = 0.f;
        #pragma unroll
        for (int g = 0; g < 8; ++g) {
            float w = __expf(mg[g] - M);
            L += w * lg[g];
            const unsigned short* op = oP + (rec0 + g) * 128 + p * 16;
            u16x8 lo = *(const u16x8*)op;
            u16x8 hi = *(const u16x8*)(op + 8);
            #pragma unroll
            for (int i = 0; i < 8; ++i) {
                acc[i]     += w * b2f(lo[i]);
                acc[8 + i] += w * b2f(hi[i]);
            }
        }
        float invL = 1.0f / L;
        #pragma unroll
        for (int i = 0; i < 16; ++i) z[a][i] = acc[i] * invL;
    }
    float sq = 0.f;
    #pragma unroll
    for (int i = 0; i < 16; ++i) { float d = z[0][i] - z[1][i]; sq += d * d; }
    #pragma unroll
    for (int off = 1; off < 64; off <<= 1) sq += __shfl_xor(sq, off);
    if ((tid & 63) == 0) red[tid >> 6] = sq;
    __syncthreads();
    if (tid == 0)
        atomicAdd(out, (red[0] + red[1] + red[2] + red[3]) * (1.0f / 1048576.0f));
}

// ============================================================================
// Fallback (R2 kernel, proven): used only if ws_size < WS_NEED.
// ============================================================================
__global__ __launch_bounds__(128) void fused_attn_mse(
    const float* __restrict__ Qm, const float* __restrict__ Km,
    const float* __restrict__ Vm, const float* __restrict__ CKm,
    const float* __restrict__ CVm, float* __restrict__ out)
{
    __shared__ __align__(16) unsigned short Kl[2][32 * D_];
    __shared__ __align__(16) unsigned short Vt[2][D_ * 40];
    __shared__ __align__(16) unsigned short Pl[2][16 * 32];
    __shared__ float red[2];

    const int tid = threadIdx.x;
    const int w = tid >> 6, lx = tid & 63, g = lx >> 4, c = lx & 15;
    const int h = blockIdx.x >> 5, qt = blockIdx.x & 31;

    bf16x8 qf[4];
    {
        const float* qrow = Qm + ((size_t)(h * Q_) + qt * 32 + w * 16 + c) * D_;
        const float scale = 0.08838834764831845f;
        #pragma unroll
        for (int dc = 0; dc < 4; ++dc) {
            const float4* p = (const float4*)(qrow + dc * 32 + 8 * g);
            float4 a = p[0], b = p[1];
            u16x8 u;
            u[0] = f2b(a.x * scale); u[1] = f2b(a.y * scale);
            u[2] = f2b(a.z * scale); u[3] = f2b(a.w * scale);
            u[4] = f2b(b.x * scale); u[5] = f2b(b.y * scale);
            u[6] = f2b(b.z * scale); u[7] = f2b(b.w * scale);
            qf[dc] = __builtin_bit_cast(bf16x8, u);
        }
    }

    f32x4 z[8];
    float sqacc = 0.f;

    for (int pass = 0; pass < 2; ++pass) {
        const int    n  = pass ? NC_ : N_;
        const float* Kh = (pass ? CKm : Km) + (size_t)h * n * D_;
        const float* Vh = (pass ? CVm : Vm) + (size_t)h * n * D_;
        const int niter = n / 32;

        auto stage_load = [&](int n0, float4 (&kr)[4][2], float (&vk)[32]) {
            #pragma unroll
            for (int w4 = 0; w4 < 4; ++w4) {
                int cid = w4 * 128 + tid, rr = cid >> 4, c8 = cid & 15;
                const float4* p = (const float4*)(Kh + (size_t)(n0 + rr) * D_ + c8 * 8);
                kr[w4][0] = p[0]; kr[w4][1] = p[1];
            }
            #pragma unroll
            for (int k = 0; k < 32; ++k) vk[k] = Vh[(size_t)(n0 + k) * D_ + tid];
        };
        auto stage_store = [&](int buf, const float4 (&kr)[4][2], const float (&vk)[32]) {
            char* Kc = (char*)Kl[buf];
            #pragma unroll
            for (int w4 = 0; w4 < 4; ++w4) {
                int cid = w4 * 128 + tid, rr = cid >> 4, c8 = cid & 15;
                u16x8 u;
                u[0] = f2b(kr[w4][0].x); u[1] = f2b(kr[w4][0].y);
                u[2] = f2b(kr[w4][0].z); u[3] = f2b(kr[w4][0].w);
                u[4] = f2b(kr[w4][1].x); u[5] = f2b(kr[w4][1].y);
                u[6] = f2b(kr[w4][1].z); u[7] = f2b(kr[w4][1].w);
                *(u16x8*)(Kc + ((rr * 256 + c8 * 16) ^ ((rr & 7) << 4))) = u;
            }
            char* Vc = (char*)Vt[buf];
            #pragma unroll
            for (int s = 0; s < 4; ++s) {
                u16x8 u;
                #pragma unroll
                for (int i = 0; i < 8; ++i) u[i] = f2b(vk[s * 8 + i]);
                *(u16x8*)(Vc + tid * 80 + s * 16) = u;
            }
        };

        f32x4 o[8];
        #pragma unroll
        for (int dt = 0; dt < 8; ++dt) o[dt] = (f32x4){0.f, 0.f, 0.f, 0.f};
        float m[4], lsum[4];
        #pragma unroll
        for (int j = 0; j < 4; ++j) { m[j] = -1e30f; lsum[j] = 0.f; }

        {
            float4 kr0[4][2]; float vk0[32];
            stage_load(0, kr0, vk0);
            stage_store(0, kr0, vk0);
        }
        __syncthreads();

        for (int it = 0; it < niter; ++it) {
            const int cur  = it & 1;
            const int more = (it + 1 < niter);
            float4 kr[4][2]; float vk[32];
            if (more) stage_load((it + 1) * 32, kr, vk);

            f32x4 s0 = (f32x4){0.f, 0.f, 0.f, 0.f};
            f32x4 s1 = (f32x4){0.f, 0.f, 0.f, 0.f};
            const char* Kc = (const char*)Kl[cur];
            #pragma unroll
            for (int dc = 0; dc < 4; ++dc) {
                bf16x8 k0 = *(const bf16x8*)(Kc + (((c) * 256      + dc * 64 + g * 16) ^ ((c & 7) << 4)));
                bf16x8 k1 = *(const bf16x8*)(Kc + (((16 + c) * 256 + dc * 64 + g * 16) ^ ((c & 7) << 4)));
                s0 = __builtin_amdgcn_mfma_f32_16x16x32_bf16(qf[dc], k0, s0, 0, 0, 0);
                s1 = __builtin_amdgcn_mfma_f32_16x16x32_bf16(qf[dc], k1, s1, 0, 0, 0);
            }
            float mx[4];
            #pragma unroll
            for (int j = 0; j < 4; ++j) mx[j] = fmaxf(s0[j], s1[j]);
            #pragma unroll
            for (int off = 1; off < 16; off <<= 1)
                #pragma unroll
                for (int j = 0; j < 4; ++j) mx[j] = fmaxf(mx[j], __shfl_xor(mx[j], off));
            int chg = 0;
            #pragma unroll
            for (int j = 0; j < 4; ++j) chg |= (mx[j] > m[j]);
            if (__any(chg)) {
                #pragma unroll
                for (int j = 0; j < 4; ++j) {
                    float mn = fmaxf(m[j], mx[j]);
                    float al = __expf(m[j] - mn);
                    m[j] = mn; lsum[j] *= al;
                    #pragma unroll
                    for (int dt = 0; dt < 8; ++dt) o[dt][j] *= al;
                }
            }
            unsigned short pb[8];
            #pragma unroll
            for (int j = 0; j < 4; ++j) {
                float p0 = __expf(s0[j] - m[j]);
                float p1 = __expf(s1[j] - m[j]);
                lsum[j] += p0 + p1;
                pb[j] = f2b(p0); pb[4 + j] = f2b(p1);
            }
            char* Pb = (char*)&Pl[w][0];
            #pragma unroll
            for (int j = 0; j < 4; ++j) {
                *(unsigned short*)(Pb + (((4 * g + j) * 64      + c * 2) ^ (g << 4))) = pb[j];
                *(unsigned short*)(Pb + (((4 * g + j) * 64 + 32 + c * 2) ^ (g << 4))) = pb[4 + j];
            }
            bf16x8 pa = *(const bf16x8*)((const char*)&Pl[w][0] +
                          ((c * 64 + g * 16) ^ (((c >> 2) & 3) << 4)));
            const char* Vc = (const char*)Vt[cur];
            #pragma unroll
            for (int dt = 0; dt < 8; ++dt) {
                bf16x8 vf = *(const bf16x8*)(Vc + (dt * 16 + c) * 80 + g * 16);
                o[dt] = __builtin_amdgcn_mfma_f32_16x16x32_bf16(pa, vf, o[dt], 0, 0, 0);
            }
            if (more) stage_store(cur ^ 1, kr, vk);
            __syncthreads();
        }

        #pragma unroll
        for (int off = 1; off < 16; off <<= 1)
            #pragma unroll
            for (int j = 0; j < 4; ++j) lsum[j] += __shfl_xor(lsum[j], off);
        float inv[4];
        #pragma unroll
        for (int j = 0; j < 4; ++j) inv[j] = 1.0f / lsum[j];

        if (pass == 0) {
            #pragma unroll
            for (int dt = 0; dt < 8; ++dt)
                #pragma unroll
                for (int j = 0; j < 4; ++j) z[dt][j] = o[dt][j] * inv[j];
        } else {
            #pragma unroll
            for (int dt = 0; dt < 8; ++dt)
                #pragma unroll
                for (int j = 0; j < 4; ++j) {
                    float d = z[dt][j] - o[dt][j] * inv[j];
                    sqacc += d * d;
                }
        }
        __syncthreads();
    }

    #pragma unroll
    for (int off = 1; off < 64; off <<= 1) sqacc += __shfl_xor(sqacc, off);
    if (lx == 0) red[w] = sqacc;
    __syncthreads();
    if (tid == 0) atomicAdd(out, (red[0] + red[1]) * (1.0f / 1048576.0f));
}

extern "C" void kernel_launch(void* const* d_in, const int* in_sizes, int n_in,
                              void* d_out, int out_size, void* d_ws, size_t ws_size,
                              hipStream_t stream) {
    const float* q  = (const float*)d_in[0];
    const float* k  = (const float*)d_in[1];
    const float* v  = (const float*)d_in[2];
    const float* ck = (const float*)d_in[3];
    const float* cv = (const float*)d_in[4];
    float* out = (float*)d_out;

    hipMemsetAsync(out, 0, sizeof(float), stream);

    if (ws_size >= WS_NEED) {
        char* ws = (char*)d_ws;
        convert_kv<<<dim3(NCHT + NCHC), dim3(256), 0, stream>>>(k, v, ck, cv, ws);
        attn_partial<<<dim3(256), dim3(512), 0, stream>>>(q, ws);
        combine_mse<<<dim3(256), dim3(256), 0, stream>>>(ws, out);
    } else {
        fused_attn_mse<<<dim3(256), dim3(128), 0, stream>>>(q, k, v, ck, cv, out);
    }
}

// Round 5
// 186.187 us; speedup vs baseline: 32.6225x; 1.1292x over previous
//
#include <hip/hip_runtime.h>
#include <hip/hip_bf16.h>

#define H_   8
#define Q_   1024
#define N_   8192
#define NC_  1024
#define D_   128

// ---- converted-KV chunk geometry (64 keys per chunk) ----
// Padded strides (272B, 144B are ≡ 4 banks mod 32) make row-varying b128
// reads conflict-free WITHOUT any XOR swizzle (the R4 XOR caused 4-way).
#define KSTR  272                      // K row stride: 16 slots + 1 pad slot
#define VOFF  17408                    // 64*KSTR
#define VSTR  144                      // V^T row stride: 8 slots + 1 pad
#define CHB   35840                    // VOFF + 128*VSTR
#define NCHT  1024                     // teacher chunks: 8h * 128
#define NCHC  128                      // compressed chunks: 8h * 16
#define O_OFF   ((size_t)(NCHT + NCHC) * CHB)
#define ML_OFF  (O_OFF + (size_t)131072 * 256)
#define WS_NEED (ML_OFF + (size_t)131072 * 8)

typedef __attribute__((ext_vector_type(8))) short          bf16x8;
typedef __attribute__((ext_vector_type(8))) unsigned short u16x8;
typedef __attribute__((ext_vector_type(4))) float          f32x4;

__device__ __forceinline__ unsigned short f2b(float x) {
    __hip_bfloat16 h = __float2bfloat16(x);   // RNE
    unsigned short u;
    __builtin_memcpy(&u, &h, sizeof(u));
    return u;
}
__device__ __forceinline__ float b2f(unsigned short u) {
    unsigned int x = ((unsigned int)u) << 16;
    float f;
    __builtin_memcpy(&f, &x, sizeof(f));
    return f;
}
__device__ __forceinline__ void async16(void* lds, const void* gsrc) {
    __builtin_amdgcn_global_load_lds(
        (const __attribute__((address_space(1))) unsigned int*)gsrc,
        (__attribute__((address_space(3))) unsigned int*)lds, 16, 0, 0);
}

// ============================================================================
// Convert: fp32 K/V -> bf16 chunks. K rows linear d (slot sl = d-octet sl),
// V^T rows linear keys. Fully coalesced reads/writes; V transposed via LDS.
// ============================================================================
__global__ __launch_bounds__(256) void convert_kv(
    const float* __restrict__ Km, const float* __restrict__ Vm,
    const float* __restrict__ CKm, const float* __restrict__ CVm,
    char* __restrict__ ws)
{
    __shared__ float vl[64 * 129];
    const int cid = blockIdx.x;        // 0..1151
    const int tid = threadIdx.x;

    const float* Kp; const float* Vp; int h, kc, n;
    if (cid < NCHT) { h = cid >> 7; kc = cid & 127; Kp = Km; Vp = Vm; n = N_; }
    else { int c2 = cid - NCHT; h = c2 >> 4; kc = c2 & 15; Kp = CKm; Vp = CVm; n = NC_; }
    const size_t base = ((size_t)h * n + (size_t)kc * 64) * D_;

    // phase 1: V[64][128] fp32 -> LDS (coalesced)
    const float4* Vg = (const float4*)(Vp + base);
    #pragma unroll
    for (int s = 0; s < 8; ++s) {
        int fi = s * 256 + tid;
        int key = fi >> 5, dp = (fi & 31) * 4;
        float4 v = Vg[fi];
        float* d = vl + key * 129 + dp;
        d[0] = v.x; d[1] = v.y; d[2] = v.z; d[3] = v.w;
    }
    __syncthreads();

    char* cb = ws + (size_t)cid * CHB;

    // phase 2: K rows, linear 16B slots (sequential global reads)
    for (int s = tid; s < 1088; s += 256) {
        int r = s / 17, sl = s - r * 17;
        if (sl < 16) {
            const float4* src = (const float4*)(Kp + base + (size_t)r * D_ + sl * 8);
            float4 a = src[0], b = src[1];
            u16x8 u;
            u[0] = f2b(a.x); u[1] = f2b(a.y); u[2] = f2b(a.z); u[3] = f2b(a.w);
            u[4] = f2b(b.x); u[5] = f2b(b.y); u[6] = f2b(b.z); u[7] = f2b(b.w);
            *(u16x8*)(cb + r * KSTR + sl * 16) = u;
        }
    }
    // phase 3: V^T rows (d'), linear key-octet slots
    for (int s = tid; s < 1152; s += 256) {
        int r = s / 9, sl = s - r * 9;          // r = d'
        if (sl < 8) {
            const float* col = vl + (sl * 8) * 129 + r;
            u16x8 u;
            #pragma unroll
            for (int i = 0; i < 8; ++i) u[i] = f2b(col[i * 129]);
            *(u16x8*)(cb + VOFF + r * VSTR + sl * 16) = u;
        }
    }
}

// ============================================================================
// Attention partials, swapped-QK^T form: S^T = mfma(A=K, B=Q) puts 4
// consecutive keys per lane -> packed b64 P-writes, 4-shfl max reduce,
// defer-max (THR=8) makes rescale (and its bpermute redistribution) rare.
// 256 blocks = 8h x 4qt x 8 kv-chunks, 8 waves x 32 q-rows, KVB=64 dbuf.
// ============================================================================
#define PSTR 144

__global__ __launch_bounds__(512, 2) void attn_partial(
    const float* __restrict__ Qm, char* __restrict__ ws)
{
    __shared__ __align__(16) char kvbuf[2][CHB];       // 71,680
    __shared__ __align__(16) char pbuf[8][32 * PSTR];  // 36,864
    const int tid = threadIdx.x;
    const int wq = tid >> 6, ln = tid & 63, g = ln >> 4, c = ln & 15;

    const int bid = blockIdx.x;
    const int xcd = bid & 7, ii = bid >> 3;
    const int pair = xcd * 8 + (ii >> 2), qt = ii & 3;
    const int h = pair >> 3, gch = pair & 7;           // h == xcd

    // ---- Q fragments (scale folded); B-frag: lane (g,c) = Q[qrow=c+16rt][d=8g+i+32dc]
    bf16x8 qf[2][4];
    {
        const float scale = 0.08838834764831845f;      // 1/sqrt(128)
        #pragma unroll
        for (int rt = 0; rt < 2; ++rt) {
            const float* qrow = Qm + ((size_t)h * Q_ + qt * 256 + wq * 32 + rt * 16 + c) * D_;
            #pragma unroll
            for (int dc = 0; dc < 4; ++dc) {
                const float4* p = (const float4*)(qrow + dc * 32 + g * 8);
                float4 a = p[0], b = p[1];
                u16x8 u;
                u[0] = f2b(a.x * scale); u[1] = f2b(a.y * scale);
                u[2] = f2b(a.z * scale); u[3] = f2b(a.w * scale);
                u[4] = f2b(b.x * scale); u[5] = f2b(b.y * scale);
                u[6] = f2b(b.z * scale); u[7] = f2b(b.w * scale);
                qf[rt][dc] = __builtin_bit_cast(bf16x8, u);
            }
        }
    }

    auto stage = [&](size_t cid, int buf) {            // 2240 linear 16B slots
        const char* s = ws + cid * CHB;
        char* d = kvbuf[buf];
        #pragma unroll
        for (int k = 0; k < 4; ++k)
            async16(d + (k * 512 + tid) * 16, s + (size_t)(k * 512 + tid) * 16);
        if (tid < 192) async16(d + (2048 + tid) * 16, s + (size_t)(2048 + tid) * 16);
    };

    f32x4 o[2][8];     // O[qrow=rt*16+4g+j][d=dt*16+c]
    float m[2], l[2];  // score layout: row = rt*16+c

    auto compute = [&](int cur) {
        const char* Kc = kvbuf[cur];
        const char* Vc = kvbuf[cur] + VOFF;
        char* Pb = pbuf[wq];

        // ---- S^T = K Q^T : lane (g,c) gets S[key=16kt+4g+j][qrow=rt*16+c]
        f32x4 s[4][2];
        #pragma unroll
        for (int kt = 0; kt < 4; ++kt)
            #pragma unroll
            for (int rt = 0; rt < 2; ++rt) s[kt][rt] = (f32x4){0.f, 0.f, 0.f, 0.f};
        #pragma unroll
        for (int dc = 0; dc < 4; ++dc) {
            #pragma unroll
            for (int kt = 0; kt < 4; ++kt) {
                bf16x8 kf = *(const bf16x8*)(Kc + (kt * 16 + c) * KSTR + dc * 64 + g * 16);
                s[kt][0] = __builtin_amdgcn_mfma_f32_16x16x32_bf16(kf, qf[0][dc], s[kt][0], 0, 0, 0);
                s[kt][1] = __builtin_amdgcn_mfma_f32_16x16x32_bf16(kf, qf[1][dc], s[kt][1], 0, 0, 0);
            }
        }
        // ---- row max (16 in-lane values per rt, then 2 shfl across g) ----
        float mx[2];
        #pragma unroll
        for (int rt = 0; rt < 2; ++rt) {
            float a = fmaxf(fmaxf(s[0][rt][0], s[0][rt][1]), fmaxf(s[0][rt][2], s[0][rt][3]));
            float b = fmaxf(fmaxf(s[1][rt][0], s[1][rt][1]), fmaxf(s[1][rt][2], s[1][rt][3]));
            float d = fmaxf(fmaxf(s[2][rt][0], s[2][rt][1]), fmaxf(s[2][rt][2], s[2][rt][3]));
            float e = fmaxf(fmaxf(s[3][rt][0], s[3][rt][1]), fmaxf(s[3][rt][2], s[3][rt][3]));
            mx[rt] = fmaxf(fmaxf(a, b), fmaxf(d, e));
        }
        #pragma unroll
        for (int rt = 0; rt < 2; ++rt) {
            mx[rt] = fmaxf(mx[rt], __shfl_xor(mx[rt], 16));
            mx[rt] = fmaxf(mx[rt], __shfl_xor(mx[rt], 32));
        }
        // ---- defer-max rescale (rare) ----
        int need = (mx[0] > m[0] + 8.f) | (mx[1] > m[1] + 8.f);
        if (__any(need)) {
            #pragma unroll
            for (int rt = 0; rt < 2; ++rt) {
                float mn = fmaxf(m[rt], mx[rt]);
                float al = __expf(m[rt] - mn);
                l[rt] *= al; m[rt] = mn;
                int ia = __builtin_bit_cast(int, al);
                #pragma unroll
                for (int j = 0; j < 4; ++j) {   // alpha of row rt*16+4g+j
                    int srcl = (ln & 48) + ((ln >> 2) & 12) + j;
                    float aj = __builtin_bit_cast(float,
                        __builtin_amdgcn_ds_bpermute(srcl << 2, ia));
                    #pragma unroll
                    for (int dt = 0; dt < 8; ++dt) o[rt][dt][j] *= aj;
                }
            }
        }
        // ---- P = exp(S - m): pack 4 consecutive keys -> one b64 write ----
        #pragma unroll
        for (int rt = 0; rt < 2; ++rt) {
            #pragma unroll
            for (int kt = 0; kt < 4; ++kt) {
                float p0 = __expf(s[kt][rt][0] - m[rt]);
                float p1 = __expf(s[kt][rt][1] - m[rt]);
                float p2 = __expf(s[kt][rt][2] - m[rt]);
                float p3 = __expf(s[kt][rt][3] - m[rt]);
                l[rt] += (p0 + p1) + (p2 + p3);
                uint2 w;
                w.x = (unsigned)f2b(p0) | ((unsigned)f2b(p1) << 16);
                w.y = (unsigned)f2b(p2) | ((unsigned)f2b(p3) << 16);
                *(uint2*)(Pb + (rt * 16 + c) * PSTR + kt * 32 + g * 8) = w;
            }
        }
        // ---- PV : A = P[qrow][keys 8g+i+32kb], B = V^T ----
        bf16x8 pa[2][2];
        #pragma unroll
        for (int rt = 0; rt < 2; ++rt)
            #pragma unroll
            for (int kb = 0; kb < 2; ++kb)
                pa[rt][kb] = *(const bf16x8*)(Pb + (rt * 16 + c) * PSTR + kb * 64 + g * 16);
        #pragma unroll
        for (int dt = 0; dt < 8; ++dt) {
            const char* vrow = Vc + (dt * 16 + c) * VSTR;
            bf16x8 v0 = *(const bf16x8*)(vrow + g * 16);
            o[0][dt] = __builtin_amdgcn_mfma_f32_16x16x32_bf16(pa[0][0], v0, o[0][dt], 0, 0, 0);
            o[1][dt] = __builtin_amdgcn_mfma_f32_16x16x32_bf16(pa[1][0], v0, o[1][dt], 0, 0, 0);
            bf16x8 v1 = *(const bf16x8*)(vrow + 64 + g * 16);
            o[0][dt] = __builtin_amdgcn_mfma_f32_16x16x32_bf16(pa[0][1], v1, o[0][dt], 0, 0, 0);
            o[1][dt] = __builtin_amdgcn_mfma_f32_16x16x32_bf16(pa[1][1], v1, o[1][dt], 0, 0, 0);
        }
    };

    auto run_pass = [&](size_t cbase, int niter) {
        #pragma unroll
        for (int rt = 0; rt < 2; ++rt) {
            #pragma unroll
            for (int dt = 0; dt < 8; ++dt) o[rt][dt] = (f32x4){0.f, 0.f, 0.f, 0.f};
            m[rt] = -1e30f; l[rt] = 0.f;
        }
        stage(cbase, 0);
        __syncthreads();
        for (int it = 0; it < niter; ++it) {
            int cur = it & 1;
            if (it + 1 < niter) stage(cbase + it + 1, cur ^ 1);
            compute(cur);
            __syncthreads();
        }
        #pragma unroll
        for (int rt = 0; rt < 2; ++rt) {   // row-sum across the 4 g-lanes
            l[rt] += __shfl_xor(l[rt], 16);
            l[rt] += __shfl_xor(l[rt], 32);
        }
    };

    auto store_partials = [&](int a) {
        unsigned short* oP = (unsigned short*)(ws + O_OFF);
        float2* mlP = (float2*)(ws + ML_OFF);
        #pragma unroll
        for (int rt = 0; rt < 2; ++rt)
            #pragma unroll
            for (int j = 0; j < 4; ++j) {
                int row_glob = h * 1024 + qt * 256 + wq * 32 + rt * 16 + 4 * g + j;
                size_t rec = ((size_t)row_glob * 2 + a) * 8 + gch;
                unsigned short* dst = oP + rec * 128 + c;
                #pragma unroll
                for (int dt = 0; dt < 8; ++dt) dst[dt * 16] = f2b(o[rt][dt][j]);
            }
        if (g == 0) {
            #pragma unroll
            for (int rt = 0; rt < 2; ++rt) {
                int row_glob = h * 1024 + qt * 256 + wq * 32 + rt * 16 + c;
                size_t rec = ((size_t)row_glob * 2 + a) * 8 + gch;
                mlP[rec] = make_float2(m[rt], l[rt]);
            }
        }
    };

    run_pass((size_t)h * 128 + gch * 16, 16);          // teacher
    store_partials(0);
    run_pass((size_t)NCHT + h * 16 + gch * 2, 2);      // compressed
    store_partials(1);
}

// ============================================================================
// Combine split-K partials (global softmax) for both attentions + fused MSE.
// ============================================================================
__global__ __launch_bounds__(256) void combine_mse(
    const char* __restrict__ ws, float* __restrict__ out)
{
    __shared__ float red[4];
    const int tid = threadIdx.x;
    const int row = blockIdx.x * 32 + (tid >> 3);
    const int p   = tid & 7;
    const unsigned short* oP = (const unsigned short*)(ws + O_OFF);
    const float2* mlP = (const float2*)(ws + ML_OFF);

    float z[2][16];
    #pragma unroll
    for (int a = 0; a < 2; ++a) {
        size_t rec0 = ((size_t)row * 2 + a) * 8;
        float mg[8], lg[8], M = -1e30f;
        #pragma unroll
        for (int g = 0; g < 8; ++g) {
            float2 t = mlP[rec0 + g];
            mg[g] = t.x; lg[g] = t.y;
            M = fmaxf(M, mg[g]);
        }
        float L = 0.f, acc[16];
        #pragma unroll
        for (int i = 0; i < 16; ++i) acc[i] = 0.f;
        #pragma unroll
        for (int g = 0; g < 8; ++g) {
            float w = __expf(mg[g] - M);
            L += w * lg[g];
            const unsigned short* op = oP + (rec0 + g) * 128 + p * 16;
            u16x8 lo = *(const u16x8*)op;
            u16x8 hi = *(const u16x8*)(op + 8);
            #pragma unroll
            for (int i = 0; i < 8; ++i) {
                acc[i]     += w * b2f(lo[i]);
                acc[8 + i] += w * b2f(hi[i]);
            }
        }
        float invL = 1.0f / L;
        #pragma unroll
        for (int i = 0; i < 16; ++i) z[a][i] = acc[i] * invL;
    }
    float sq = 0.f;
    #pragma unroll
    for (int i = 0; i < 16; ++i) { float d = z[0][i] - z[1][i]; sq += d * d; }
    #pragma unroll
    for (int off = 1; off < 64; off <<= 1) sq += __shfl_xor(sq, off);
    if ((tid & 63) == 0) red[tid >> 6] = sq;
    __syncthreads();
    if (tid == 0)
        atomicAdd(out, (red[0] + red[1] + red[2] + red[3]) * (1.0f / 1048576.0f));
}

// ============================================================================
// Fallback (R2 kernel, proven): used only if ws_size < WS_NEED.
// ============================================================================
__global__ __launch_bounds__(128) void fused_attn_mse(
    const float* __restrict__ Qm, const float* __restrict__ Km,
    const float* __restrict__ Vm, const float* __restrict__ CKm,
    const float* __restrict__ CVm, float* __restrict__ out)
{
    __shared__ __align__(16) unsigned short Kl[2][32 * D_];
    __shared__ __align__(16) unsigned short Vt[2][D_ * 40];
    __shared__ __align__(16) unsigned short Pl[2][16 * 32];
    __shared__ float red[2];

    const int tid = threadIdx.x;
    const int w = tid >> 6, lx = tid & 63, g = lx >> 4, c = lx & 15;
    const int h = blockIdx.x >> 5, qt = blockIdx.x & 31;

    bf16x8 qf[4];
    {
        const float* qrow = Qm + ((size_t)(h * Q_) + qt * 32 + w * 16 + c) * D_;
        const float scale = 0.08838834764831845f;
        #pragma unroll
        for (int dc = 0; dc < 4; ++dc) {
            const float4* p = (const float4*)(qrow + dc * 32 + 8 * g);
            float4 a = p[0], b = p[1];
            u16x8 u;
            u[0] = f2b(a.x * scale); u[1] = f2b(a.y * scale);
            u[2] = f2b(a.z * scale); u[3] = f2b(a.w * scale);
            u[4] = f2b(b.x * scale); u[5] = f2b(b.y * scale);
            u[6] = f2b(b.z * scale); u[7] = f2b(b.w * scale);
            qf[dc] = __builtin_bit_cast(bf16x8, u);
        }
    }

    f32x4 z[8];
    float sqacc = 0.f;

    for (int pass = 0; pass < 2; ++pass) {
        const int    n  = pass ? NC_ : N_;
        const float* Kh = (pass ? CKm : Km) + (size_t)h * n * D_;
        const float* Vh = (pass ? CVm : Vm) + (size_t)h * n * D_;
        const int niter = n / 32;

        auto stage_load = [&](int n0, float4 (&kr)[4][2], float (&vk)[32]) {
            #pragma unroll
            for (int w4 = 0; w4 < 4; ++w4) {
                int cid = w4 * 128 + tid, rr = cid >> 4, c8 = cid & 15;
                const float4* p = (const float4*)(Kh + (size_t)(n0 + rr) * D_ + c8 * 8);
                kr[w4][0] = p[0]; kr[w4][1] = p[1];
            }
            #pragma unroll
            for (int k = 0; k < 32; ++k) vk[k] = Vh[(size_t)(n0 + k) * D_ + tid];
        };
        auto stage_store = [&](int buf, const float4 (&kr)[4][2], const float (&vk)[32]) {
            char* Kc = (char*)Kl[buf];
            #pragma unroll
            for (int w4 = 0; w4 < 4; ++w4) {
                int cid = w4 * 128 + tid, rr = cid >> 4, c8 = cid & 15;
                u16x8 u;
                u[0] = f2b(kr[w4][0].x); u[1] = f2b(kr[w4][0].y);
                u[2] = f2b(kr[w4][0].z); u[3] = f2b(kr[w4][0].w);
                u[4] = f2b(kr[w4][1].x); u[5] = f2b(kr[w4][1].y);
                u[6] = f2b(kr[w4][1].z); u[7] = f2b(kr[w4][1].w);
                *(u16x8*)(Kc + ((rr * 256 + c8 * 16) ^ ((rr & 7) << 4))) = u;
            }
            char* Vc = (char*)Vt[buf];
            #pragma unroll
            for (int s = 0; s < 4; ++s) {
                u16x8 u;
                #pragma unroll
                for (int i = 0; i < 8; ++i) u[i] = f2b(vk[s * 8 + i]);
                *(u16x8*)(Vc + tid * 80 + s * 16) = u;
            }
        };

        f32x4 o[8];
        #pragma unroll
        for (int dt = 0; dt < 8; ++dt) o[dt] = (f32x4){0.f, 0.f, 0.f, 0.f};
        float m[4], lsum[4];
        #pragma unroll
        for (int j = 0; j < 4; ++j) { m[j] = -1e30f; lsum[j] = 0.f; }

        {
            float4 kr0[4][2]; float vk0[32];
            stage_load(0, kr0, vk0);
            stage_store(0, kr0, vk0);
        }
        __syncthreads();

        for (int it = 0; it < niter; ++it) {
            const int cur  = it & 1;
            const int more = (it + 1 < niter);
            float4 kr[4][2]; float vk[32];
            if (more) stage_load((it + 1) * 32, kr, vk);

            f32x4 s0 = (f32x4){0.f, 0.f, 0.f, 0.f};
            f32x4 s1 = (f32x4){0.f, 0.f, 0.f, 0.f};
            const char* Kc = (const char*)Kl[cur];
            #pragma unroll
            for (int dc = 0; dc < 4; ++dc) {
                bf16x8 k0 = *(const bf16x8*)(Kc + (((c) * 256      + dc * 64 + g * 16) ^ ((c & 7) << 4)));
                bf16x8 k1 = *(const bf16x8*)(Kc + (((16 + c) * 256 + dc * 64 + g * 16) ^ ((c & 7) << 4)));
                s0 = __builtin_amdgcn_mfma_f32_16x16x32_bf16(qf[dc], k0, s0, 0, 0, 0);
                s1 = __builtin_amdgcn_mfma_f32_16x16x32_bf16(qf[dc], k1, s1, 0, 0, 0);
            }
            float mx[4];
            #pragma unroll
            for (int j = 0; j < 4; ++j) mx[j] = fmaxf(s0[j], s1[j]);
            #pragma unroll
            for (int off = 1; off < 16; off <<= 1)
                #pragma unroll
                for (int j = 0; j < 4; ++j) mx[j] = fmaxf(mx[j], __shfl_xor(mx[j], off));
            int chg = 0;
            #pragma unroll
            for (int j = 0; j < 4; ++j) chg |= (mx[j] > m[j]);
            if (__any(chg)) {
                #pragma unroll
                for (int j = 0; j < 4; ++j) {
                    float mn = fmaxf(m[j], mx[j]);
                    float al = __expf(m[j] - mn);
                    m[j] = mn; lsum[j] *= al;
                    #pragma unroll
                    for (int dt = 0; dt < 8; ++dt) o[dt][j] *= al;
                }
            }
            unsigned short pb[8];
            #pragma unroll
            for (int j = 0; j < 4; ++j) {
                float p0 = __expf(s0[j] - m[j]);
                float p1 = __expf(s1[j] - m[j]);
                lsum[j] += p0 + p1;
                pb[j] = f2b(p0); pb[4 + j] = f2b(p1);
            }
            char* Pb = (char*)&Pl[w][0];
            #pragma unroll
            for (int j = 0; j < 4; ++j) {
                *(unsigned short*)(Pb + (((4 * g + j) * 64      + c * 2) ^ (g << 4))) = pb[j];
                *(unsigned short*)(Pb + (((4 * g + j) * 64 + 32 + c * 2) ^ (g << 4))) = pb[4 + j];
            }
            bf16x8 pa = *(const bf16x8*)((const char*)&Pl[w][0] +
                          ((c * 64 + g * 16) ^ (((c >> 2) & 3) << 4)));
            const char* Vc = (const char*)Vt[cur];
            #pragma unroll
            for (int dt = 0; dt < 8; ++dt) {
                bf16x8 vf = *(const bf16x8*)(Vc + (dt * 16 + c) * 80 + g * 16);
                o[dt] = __builtin_amdgcn_mfma_f32_16x16x32_bf16(pa, vf, o[dt], 0, 0, 0);
            }
            if (more) stage_store(cur ^ 1, kr, vk);
            __syncthreads();
        }

        #pragma unroll
        for (int off = 1; off < 16; off <<= 1)
            #pragma unroll
            for (int j = 0; j < 4; ++j) lsum[j] += __shfl_xor(lsum[j], off);
        float inv[4];
        #pragma unroll
        for (int j = 0; j < 4; ++j) inv[j] = 1.0f / lsum[j];

        if (pass == 0) {
            #pragma unroll
            for (int dt = 0; dt < 8; ++dt)
                #pragma unroll
                for (int j = 0; j < 4; ++j) z[dt][j] = o[dt][j] * inv[j];
        } else {
            #pragma unroll
            for (int dt = 0; dt < 8; ++dt)
                #pragma unroll
                for (int j = 0; j < 4; ++j) {
                    float d = z[dt][j] - o[dt][j] * inv[j];
                    sqacc += d * d;
                }
        }
        __syncthreads();
    }

    #pragma unroll
    for (int off = 1; off < 64; off <<= 1) sqacc += __shfl_xor(sqacc, off);
    if (lx == 0) red[w] = sqacc;
    __syncthreads();
    if (tid == 0) atomicAdd(out, (red[0] + red[1]) * (1.0f / 1048576.0f));
}

extern "C" void kernel_launch(void* const* d_in, const int* in_sizes, int n_in,
                              void* d_out, int out_size, void* d_ws, size_t ws_size,
                              hipStream_t stream) {
    const float* q  = (const float*)d_in[0];
    const float* k  = (const float*)d_in[1];
    const float* v  = (const float*)d_in[2];
    const float* ck = (const float*)d_in[3];
    const float* cv = (const float*)d_in[4];
    float* out = (float*)d_out;

    hipMemsetAsync(out, 0, sizeof(float), stream);

    if (ws_size >= WS_NEED) {
        char* ws = (char*)d_ws;
        convert_kv<<<dim3(NCHT + NCHC), dim3(256), 0, stream>>>(k, v, ck, cv, ws);
        attn_partial<<<dim3(256), dim3(512), 0, stream>>>(q, ws);
        combine_mse<<<dim3(256), dim3(256), 0, stream>>>(ws, out);
    } else {
        fused_attn_mse<<<dim3(256), dim3(128), 0, stream>>>(q, k, v, ck, cv, out);
    }
}

// Round 6
// 180.106 us; speedup vs baseline: 33.7240x; 1.0338x over previous
//
#include <hip/hip_runtime.h>
#include <hip/hip_bf16.h>

#define H_   8
#define Q_   1024
#define N_   8192
#define NC_  1024
#define D_   128

// ---- converted-KV chunk geometry (64 keys per chunk) ----
#define KSTR  272                      // K row stride (pad slot -> bank spread)
#define VOFF  17408                    // 64*KSTR
#define VSTR  144                      // V^T row stride
#define CHB   35840                    // VOFF + 128*VSTR  (= 2240 16B slots)
#define NCHT  1024                     // teacher chunks: 8h * 128
#define NCHC  128                      // compressed chunks: 8h * 16
#define O_OFF   ((size_t)(NCHT + NCHC) * CHB)
#define ML_OFF  (O_OFF + (size_t)131072 * 256)
#define WS_NEED (ML_OFF + (size_t)131072 * 8)   // 75,890,688 (proven to fit)

typedef __attribute__((ext_vector_type(8))) short          bf16x8;
typedef __attribute__((ext_vector_type(8))) unsigned short u16x8;
typedef __attribute__((ext_vector_type(4))) float          f32x4;

__device__ __forceinline__ unsigned short f2b(float x) {
    __hip_bfloat16 h = __float2bfloat16(x);   // RNE
    unsigned short u;
    __builtin_memcpy(&u, &h, sizeof(u));
    return u;
}
__device__ __forceinline__ float b2f(unsigned short u) {
    unsigned int x = ((unsigned int)u) << 16;
    float f;
    __builtin_memcpy(&f, &x, sizeof(f));
    return f;
}
__device__ __forceinline__ void async16(void* lds, const void* gsrc) {
    __builtin_amdgcn_global_load_lds(
        (const __attribute__((address_space(1))) unsigned int*)gsrc,
        (__attribute__((address_space(3))) unsigned int*)lds, 16, 0, 0);
}

// ============================================================================
// Convert: fp32 K/V -> bf16 chunks (unchanged from R5; coalesced, proven).
// ============================================================================
__global__ __launch_bounds__(256) void convert_kv(
    const float* __restrict__ Km, const float* __restrict__ Vm,
    const float* __restrict__ CKm, const float* __restrict__ CVm,
    char* __restrict__ ws)
{
    __shared__ float vl[64 * 129];
    const int cid = blockIdx.x;        // 0..1151
    const int tid = threadIdx.x;

    const float* Kp; const float* Vp; int h, kc, n;
    if (cid < NCHT) { h = cid >> 7; kc = cid & 127; Kp = Km; Vp = Vm; n = N_; }
    else { int c2 = cid - NCHT; h = c2 >> 4; kc = c2 & 15; Kp = CKm; Vp = CVm; n = NC_; }
    const size_t base = ((size_t)h * n + (size_t)kc * 64) * D_;

    const float4* Vg = (const float4*)(Vp + base);
    #pragma unroll
    for (int s = 0; s < 8; ++s) {
        int fi = s * 256 + tid;
        int key = fi >> 5, dp = (fi & 31) * 4;
        float4 v = Vg[fi];
        float* d = vl + key * 129 + dp;
        d[0] = v.x; d[1] = v.y; d[2] = v.z; d[3] = v.w;
    }
    __syncthreads();

    char* cb = ws + (size_t)cid * CHB;

    for (int s = tid; s < 1088; s += 256) {
        int r = s / 17, sl = s - r * 17;
        if (sl < 16) {
            const float4* src = (const float4*)(Kp + base + (size_t)r * D_ + sl * 8);
            float4 a = src[0], b = src[1];
            u16x8 u;
            u[0] = f2b(a.x); u[1] = f2b(a.y); u[2] = f2b(a.z); u[3] = f2b(a.w);
            u[4] = f2b(b.x); u[5] = f2b(b.y); u[6] = f2b(b.z); u[7] = f2b(b.w);
            *(u16x8*)(cb + r * KSTR + sl * 16) = u;
        }
    }
    for (int s = tid; s < 1152; s += 256) {
        int r = s / 9, sl = s - r * 9;          // r = d'
        if (sl < 8) {
            const float* col = vl + (sl * 8) * 129 + r;
            u16x8 u;
            #pragma unroll
            for (int i = 0; i < 8; ++i) u[i] = f2b(col[i * 129]);
            *(u16x8*)(cb + VOFF + r * VSTR + sl * 16) = u;
        }
    }
}

// ============================================================================
// Attention partials: layouts identical to R5 (proven). NEW: triple-buffered
// KV, raw s_barrier + counted vmcnt (never 0 mid-loop), setprio around MFMA.
// ============================================================================
#define PSTR 144

__global__ __launch_bounds__(512, 1) void attn_partial(
    const float* __restrict__ Qm, char* __restrict__ ws)
{
    __shared__ __align__(16) char kvbuf[3][CHB];       // 107,520
    __shared__ __align__(16) char pbuf[8][32 * PSTR];  // 36,864  -> 144,384 total
    const int tid = threadIdx.x;
    const int wq = tid >> 6, ln = tid & 63, g = ln >> 4, c = ln & 15;

    const int bid = blockIdx.x;
    const int xcd = bid & 7, ii = bid >> 3;
    const int pair = xcd * 8 + (ii >> 2), qt = ii & 3;
    const int h = pair >> 3, gch = pair & 7;           // h == xcd

    // ---- Q fragments (scale folded) ----
    bf16x8 qf[2][4];
    {
        const float scale = 0.08838834764831845f;      // 1/sqrt(128)
        #pragma unroll
        for (int rt = 0; rt < 2; ++rt) {
            const float* qrow = Qm + ((size_t)h * Q_ + qt * 256 + wq * 32 + rt * 16 + c) * D_;
            #pragma unroll
            for (int dc = 0; dc < 4; ++dc) {
                const float4* p = (const float4*)(qrow + dc * 32 + g * 8);
                float4 a = p[0], b = p[1];
                u16x8 u;
                u[0] = f2b(a.x * scale); u[1] = f2b(a.y * scale);
                u[2] = f2b(a.z * scale); u[3] = f2b(a.w * scale);
                u[4] = f2b(b.x * scale); u[5] = f2b(b.y * scale);
                u[6] = f2b(b.z * scale); u[7] = f2b(b.w * scale);
                qf[rt][dc] = __builtin_bit_cast(bf16x8, u);
            }
        }
    }

    auto stage = [&](size_t cid, int buf) {  // 2240 slots: waves 0-2: 5 instr, 3-7: 4
        const char* s = ws + cid * CHB;
        char* d = kvbuf[buf];
        #pragma unroll
        for (int k = 0; k < 4; ++k)
            async16(d + (k * 512 + tid) * 16, s + (size_t)(k * 512 + tid) * 16);
        if (tid < 192) async16(d + (2048 + tid) * 16, s + (size_t)(2048 + tid) * 16);
    };

    f32x4 o[2][8];     // O[qrow=rt*16+4g+j][d=dt*16+c]
    float m[2], l[2];  // score layout: row = rt*16+c

    auto compute = [&](int cur) {
        const char* Kc = kvbuf[cur];
        const char* Vc = kvbuf[cur] + VOFF;
        char* Pb = pbuf[wq];

        // ---- S^T = K Q^T ----
        f32x4 s[4][2];
        #pragma unroll
        for (int kt = 0; kt < 4; ++kt)
            #pragma unroll
            for (int rt = 0; rt < 2; ++rt) s[kt][rt] = (f32x4){0.f, 0.f, 0.f, 0.f};
        __builtin_amdgcn_s_setprio(1);
        #pragma unroll
        for (int dc = 0; dc < 4; ++dc) {
            #pragma unroll
            for (int kt = 0; kt < 4; ++kt) {
                bf16x8 kf = *(const bf16x8*)(Kc + (kt * 16 + c) * KSTR + dc * 64 + g * 16);
                s[kt][0] = __builtin_amdgcn_mfma_f32_16x16x32_bf16(kf, qf[0][dc], s[kt][0], 0, 0, 0);
                s[kt][1] = __builtin_amdgcn_mfma_f32_16x16x32_bf16(kf, qf[1][dc], s[kt][1], 0, 0, 0);
            }
        }
        __builtin_amdgcn_s_setprio(0);
        // ---- row max ----
        float mx[2];
        #pragma unroll
        for (int rt = 0; rt < 2; ++rt) {
            float a = fmaxf(fmaxf(s[0][rt][0], s[0][rt][1]), fmaxf(s[0][rt][2], s[0][rt][3]));
            float b = fmaxf(fmaxf(s[1][rt][0], s[1][rt][1]), fmaxf(s[1][rt][2], s[1][rt][3]));
            float d = fmaxf(fmaxf(s[2][rt][0], s[2][rt][1]), fmaxf(s[2][rt][2], s[2][rt][3]));
            float e = fmaxf(fmaxf(s[3][rt][0], s[3][rt][1]), fmaxf(s[3][rt][2], s[3][rt][3]));
            mx[rt] = fmaxf(fmaxf(a, b), fmaxf(d, e));
        }
        #pragma unroll
        for (int rt = 0; rt < 2; ++rt) {
            mx[rt] = fmaxf(mx[rt], __shfl_xor(mx[rt], 16));
            mx[rt] = fmaxf(mx[rt], __shfl_xor(mx[rt], 32));
        }
        // ---- defer-max rescale (rare) ----
        int need = (mx[0] > m[0] + 8.f) | (mx[1] > m[1] + 8.f);
        if (__any(need)) {
            #pragma unroll
            for (int rt = 0; rt < 2; ++rt) {
                float mn = fmaxf(m[rt], mx[rt]);
                float al = __expf(m[rt] - mn);
                l[rt] *= al; m[rt] = mn;
                int ia = __builtin_bit_cast(int, al);
                #pragma unroll
                for (int j = 0; j < 4; ++j) {
                    int srcl = (ln & 48) + ((ln >> 2) & 12) + j;
                    float aj = __builtin_bit_cast(float,
                        __builtin_amdgcn_ds_bpermute(srcl << 2, ia));
                    #pragma unroll
                    for (int dt = 0; dt < 8; ++dt) o[rt][dt][j] *= aj;
                }
            }
        }
        // ---- P = exp(S - m) -> LDS ----
        #pragma unroll
        for (int rt = 0; rt < 2; ++rt) {
            #pragma unroll
            for (int kt = 0; kt < 4; ++kt) {
                float p0 = __expf(s[kt][rt][0] - m[rt]);
                float p1 = __expf(s[kt][rt][1] - m[rt]);
                float p2 = __expf(s[kt][rt][2] - m[rt]);
                float p3 = __expf(s[kt][rt][3] - m[rt]);
                l[rt] += (p0 + p1) + (p2 + p3);
                uint2 w;
                w.x = (unsigned)f2b(p0) | ((unsigned)f2b(p1) << 16);
                w.y = (unsigned)f2b(p2) | ((unsigned)f2b(p3) << 16);
                *(uint2*)(Pb + (rt * 16 + c) * PSTR + kt * 32 + g * 8) = w;
            }
        }
        // ---- PV ----
        bf16x8 pa[2][2];
        #pragma unroll
        for (int rt = 0; rt < 2; ++rt)
            #pragma unroll
            for (int kb = 0; kb < 2; ++kb)
                pa[rt][kb] = *(const bf16x8*)(Pb + (rt * 16 + c) * PSTR + kb * 64 + g * 16);
        __builtin_amdgcn_s_setprio(1);
        #pragma unroll
        for (int dt = 0; dt < 8; ++dt) {
            const char* vrow = Vc + (dt * 16 + c) * VSTR;
            bf16x8 v0 = *(const bf16x8*)(vrow + g * 16);
            o[0][dt] = __builtin_amdgcn_mfma_f32_16x16x32_bf16(pa[0][0], v0, o[0][dt], 0, 0, 0);
            o[1][dt] = __builtin_amdgcn_mfma_f32_16x16x32_bf16(pa[1][0], v0, o[1][dt], 0, 0, 0);
            bf16x8 v1 = *(const bf16x8*)(vrow + 64 + g * 16);
            o[0][dt] = __builtin_amdgcn_mfma_f32_16x16x32_bf16(pa[0][1], v1, o[0][dt], 0, 0, 0);
            o[1][dt] = __builtin_amdgcn_mfma_f32_16x16x32_bf16(pa[1][1], v1, o[1][dt], 0, 0, 0);
        }
        __builtin_amdgcn_s_setprio(0);
    };

    // counted-vmcnt pipelined pass: [wait][barrier][compute(t)][stage(t+2)]
    auto run_pass = [&](size_t cbase, int niter) {
        #pragma unroll
        for (int rt = 0; rt < 2; ++rt) {
            #pragma unroll
            for (int dt = 0; dt < 8; ++dt) o[rt][dt] = (f32x4){0.f, 0.f, 0.f, 0.f};
            m[rt] = -1e30f; l[rt] = 0.f;
        }
        __syncthreads();                    // prior pass / prologue LDS quiesced
        stage(cbase + 0, 0);
        if (niter > 1) stage(cbase + 1, 1);
        int cur = 0, nxt = 2;               // nxt = (t+2)%3
        for (int t = 0; t < niter; ++t) {
            const int rem = niter - 1 - t;  // stages in flight beyond tile t
            if (wq < 3) {                   // 5 loads/stage waves
                if (rem >= 2)      asm volatile("s_waitcnt vmcnt(10)" ::: "memory");
                else if (rem == 1) asm volatile("s_waitcnt vmcnt(5)"  ::: "memory");
                else               asm volatile("s_waitcnt vmcnt(0)"  ::: "memory");
            } else {                        // 4 loads/stage waves
                if (rem >= 2)      asm volatile("s_waitcnt vmcnt(8)"  ::: "memory");
                else if (rem == 1) asm volatile("s_waitcnt vmcnt(4)"  ::: "memory");
                else               asm volatile("s_waitcnt vmcnt(0)"  ::: "memory");
            }
            __builtin_amdgcn_sched_barrier(0);
            __builtin_amdgcn_s_barrier();
            __builtin_amdgcn_sched_barrier(0);
            compute(cur);
            if (t + 2 < niter) stage(cbase + t + 2, nxt);
            cur = (cur == 2) ? 0 : cur + 1;
            nxt = (nxt == 2) ? 0 : nxt + 1;
        }
        #pragma unroll
        for (int rt = 0; rt < 2; ++rt) {
            l[rt] += __shfl_xor(l[rt], 16);
            l[rt] += __shfl_xor(l[rt], 32);
        }
    };

    auto store_partials = [&](int a) {
        unsigned short* oP = (unsigned short*)(ws + O_OFF);
        float2* mlP = (float2*)(ws + ML_OFF);
        #pragma unroll
        for (int rt = 0; rt < 2; ++rt)
            #pragma unroll
            for (int j = 0; j < 4; ++j) {
                int row_glob = h * 1024 + qt * 256 + wq * 32 + rt * 16 + 4 * g + j;
                size_t rec = ((size_t)row_glob * 2 + a) * 8 + gch;
                unsigned short* dst = oP + rec * 128 + c;
                #pragma unroll
                for (int dt = 0; dt < 8; ++dt) dst[dt * 16] = f2b(o[rt][dt][j]);
            }
        if (g == 0) {
            #pragma unroll
            for (int rt = 0; rt < 2; ++rt) {
                int row_glob = h * 1024 + qt * 256 + wq * 32 + rt * 16 + c;
                size_t rec = ((size_t)row_glob * 2 + a) * 8 + gch;
                mlP[rec] = make_float2(m[rt], l[rt]);
            }
        }
    };

    run_pass((size_t)h * 128 + gch * 16, 16);          // teacher
    store_partials(0);
    run_pass((size_t)NCHT + h * 16 + gch * 2, 2);      // compressed
    store_partials(1);
}

// ============================================================================
// Combine split-K partials + fused MSE (unchanged from R5).
// ============================================================================
__global__ __launch_bounds__(256) void combine_mse(
    const char* __restrict__ ws, float* __restrict__ out)
{
    __shared__ float red[4];
    const int tid = threadIdx.x;
    const int row = blockIdx.x * 32 + (tid >> 3);
    const int p   = tid & 7;
    const unsigned short* oP = (const unsigned short*)(ws + O_OFF);
    const float2* mlP = (const float2*)(ws + ML_OFF);

    float z[2][16];
    #pragma unroll
    for (int a = 0; a < 2; ++a) {
        size_t rec0 = ((size_t)row * 2 + a) * 8;
        float mg[8], lg[8], M = -1e30f;
        #pragma unroll
        for (int g = 0; g < 8; ++g) {
            float2 t = mlP[rec0 + g];
            mg[g] = t.x; lg[g] = t.y;
            M = fmaxf(M, mg[g]);
        }
        float L = 0.f, acc[16];
        #pragma unroll
        for (int i = 0; i < 16; ++i) acc[i] = 0.f;
        #pragma unroll
        for (int g = 0; g < 8; ++g) {
            float w = __expf(mg[g] - M);
            L += w * lg[g];
            const unsigned short* op = oP + (rec0 + g) * 128 + p * 16;
            u16x8 lo = *(const u16x8*)op;
            u16x8 hi = *(const u16x8*)(op + 8);
            #pragma unroll
            for (int i = 0; i < 8; ++i) {
                acc[i]     += w * b2f(lo[i]);
                acc[8 + i] += w * b2f(hi[i]);
            }
        }
        float invL = 1.0f / L;
        #pragma unroll
        for (int i = 0; i < 16; ++i) z[a][i] = acc[i] * invL;
    }
    float sq = 0.f;
    #pragma unroll
    for (int i = 0; i < 16; ++i) { float d = z[0][i] - z[1][i]; sq += d * d; }
    #pragma unroll
    for (int off = 1; off < 64; off <<= 1) sq += __shfl_xor(sq, off);
    if ((tid & 63) == 0) red[tid >> 6] = sq;
    __syncthreads();
    if (tid == 0)
        atomicAdd(out, (red[0] + red[1] + red[2] + red[3]) * (1.0f / 1048576.0f));
}

// ============================================================================
// Fallback (R2 kernel, proven): used only if ws_size < WS_NEED.
// ============================================================================
__global__ __launch_bounds__(128) void fused_attn_mse(
    const float* __restrict__ Qm, const float* __restrict__ Km,
    const float* __restrict__ Vm, const float* __restrict__ CKm,
    const float* __restrict__ CVm, float* __restrict__ out)
{
    __shared__ __align__(16) unsigned short Kl[2][32 * D_];
    __shared__ __align__(16) unsigned short Vt[2][D_ * 40];
    __shared__ __align__(16) unsigned short Pl[2][16 * 32];
    __shared__ float red[2];

    const int tid = threadIdx.x;
    const int w = tid >> 6, lx = tid & 63, g = lx >> 4, c = lx & 15;
    const int h = blockIdx.x >> 5, qt = blockIdx.x & 31;

    bf16x8 qf[4];
    {
        const float* qrow = Qm + ((size_t)(h * Q_) + qt * 32 + w * 16 + c) * D_;
        const float scale = 0.08838834764831845f;
        #pragma unroll
        for (int dc = 0; dc < 4; ++dc) {
            const float4* p = (const float4*)(qrow + dc * 32 + 8 * g);
            float4 a = p[0], b = p[1];
            u16x8 u;
            u[0] = f2b(a.x * scale); u[1] = f2b(a.y * scale);
            u[2] = f2b(a.z * scale); u[3] = f2b(a.w * scale);
            u[4] = f2b(b.x * scale); u[5] = f2b(b.y * scale);
            u[6] = f2b(b.z * scale); u[7] = f2b(b.w * scale);
            qf[dc] = __builtin_bit_cast(bf16x8, u);
        }
    }

    f32x4 z[8];
    float sqacc = 0.f;

    for (int pass = 0; pass < 2; ++pass) {
        const int    n  = pass ? NC_ : N_;
        const float* Kh = (pass ? CKm : Km) + (size_t)h * n * D_;
        const float* Vh = (pass ? CVm : Vm) + (size_t)h * n * D_;
        const int niter = n / 32;

        auto stage_load = [&](int n0, float4 (&kr)[4][2], float (&vk)[32]) {
            #pragma unroll
            for (int w4 = 0; w4 < 4; ++w4) {
                int cid = w4 * 128 + tid, rr = cid >> 4, c8 = cid & 15;
                const float4* p = (const float4*)(Kh + (size_t)(n0 + rr) * D_ + c8 * 8);
                kr[w4][0] = p[0]; kr[w4][1] = p[1];
            }
            #pragma unroll
            for (int k = 0; k < 32; ++k) vk[k] = Vh[(size_t)(n0 + k) * D_ + tid];
        };
        auto stage_store = [&](int buf, const float4 (&kr)[4][2], const float (&vk)[32]) {
            char* Kc = (char*)Kl[buf];
            #pragma unroll
            for (int w4 = 0; w4 < 4; ++w4) {
                int cid = w4 * 128 + tid, rr = cid >> 4, c8 = cid & 15;
                u16x8 u;
                u[0] = f2b(kr[w4][0].x); u[1] = f2b(kr[w4][0].y);
                u[2] = f2b(kr[w4][0].z); u[3] = f2b(kr[w4][0].w);
                u[4] = f2b(kr[w4][1].x); u[5] = f2b(kr[w4][1].y);
                u[6] = f2b(kr[w4][1].z); u[7] = f2b(kr[w4][1].w);
                *(u16x8*)(Kc + ((rr * 256 + c8 * 16) ^ ((rr & 7) << 4))) = u;
            }
            char* Vc = (char*)Vt[buf];
            #pragma unroll
            for (int s = 0; s < 4; ++s) {
                u16x8 u;
                #pragma unroll
                for (int i = 0; i < 8; ++i) u[i] = f2b(vk[s * 8 + i]);
                *(u16x8*)(Vc + tid * 80 + s * 16) = u;
            }
        };

        f32x4 o[8];
        #pragma unroll
        for (int dt = 0; dt < 8; ++dt) o[dt] = (f32x4){0.f, 0.f, 0.f, 0.f};
        float m[4], lsum[4];
        #pragma unroll
        for (int j = 0; j < 4; ++j) { m[j] = -1e30f; lsum[j] = 0.f; }

        {
            float4 kr0[4][2]; float vk0[32];
            stage_load(0, kr0, vk0);
            stage_store(0, kr0, vk0);
        }
        __syncthreads();

        for (int it = 0; it < niter; ++it) {
            const int cur  = it & 1;
            const int more = (it + 1 < niter);
            float4 kr[4][2]; float vk[32];
            if (more) stage_load((it + 1) * 32, kr, vk);

            f32x4 s0 = (f32x4){0.f, 0.f, 0.f, 0.f};
            f32x4 s1 = (f32x4){0.f, 0.f, 0.f, 0.f};
            const char* Kc = (const char*)Kl[cur];
            #pragma unroll
            for (int dc = 0; dc < 4; ++dc) {
                bf16x8 k0 = *(const bf16x8*)(Kc + (((c) * 256      + dc * 64 + g * 16) ^ ((c & 7) << 4)));
                bf16x8 k1 = *(const bf16x8*)(Kc + (((16 + c) * 256 + dc * 64 + g * 16) ^ ((c & 7) << 4)));
                s0 = __builtin_amdgcn_mfma_f32_16x16x32_bf16(qf[dc], k0, s0, 0, 0, 0);
                s1 = __builtin_amdgcn_mfma_f32_16x16x32_bf16(qf[dc], k1, s1, 0, 0, 0);
            }
            float mx[4];
            #pragma unroll
            for (int j = 0; j < 4; ++j) mx[j] = fmaxf(s0[j], s1[j]);
            #pragma unroll
            for (int off = 1; off < 16; off <<= 1)
                #pragma unroll
                for (int j = 0; j < 4; ++j) mx[j] = fmaxf(mx[j], __shfl_xor(mx[j], off));
            int chg = 0;
            #pragma unroll
            for (int j = 0; j < 4; ++j) chg |= (mx[j] > m[j]);
            if (__any(chg)) {
                #pragma unroll
                for (int j = 0; j < 4; ++j) {
                    float mn = fmaxf(m[j], mx[j]);
                    float al = __expf(m[j] - mn);
                    m[j] = mn; lsum[j] *= al;
                    #pragma unroll
                    for (int dt = 0; dt < 8; ++dt) o[dt][j] *= al;
                }
            }
            unsigned short pb[8];
            #pragma unroll
            for (int j = 0; j < 4; ++j) {
                float p0 = __expf(s0[j] - m[j]);
                float p1 = __expf(s1[j] - m[j]);
                lsum[j] += p0 + p1;
                pb[j] = f2b(p0); pb[4 + j] = f2b(p1);
            }
            char* Pb = (char*)&Pl[w][0];
            #pragma unroll
            for (int j = 0; j < 4; ++j) {
                *(unsigned short*)(Pb + (((4 * g + j) * 64      + c * 2) ^ (g << 4))) = pb[j];
                *(unsigned short*)(Pb + (((4 * g + j) * 64 + 32 + c * 2) ^ (g << 4))) = pb[4 + j];
            }
            bf16x8 pa = *(const bf16x8*)((const char*)&Pl[w][0] +
                          ((c * 64 + g * 16) ^ (((c >> 2) & 3) << 4)));
            const char* Vc = (const char*)Vt[cur];
            #pragma unroll
            for (int dt = 0; dt < 8; ++dt) {
                bf16x8 vf = *(const bf16x8*)(Vc + (dt * 16 + c) * 80 + g * 16);
                o[dt] = __builtin_amdgcn_mfma_f32_16x16x32_bf16(pa, vf, o[dt], 0, 0, 0);
            }
            if (more) stage_store(cur ^ 1, kr, vk);
            __syncthreads();
        }

        #pragma unroll
        for (int off = 1; off < 16; off <<= 1)
            #pragma unroll
            for (int j = 0; j < 4; ++j) lsum[j] += __shfl_xor(lsum[j], off);
        float inv[4];
        #pragma unroll
        for (int j = 0; j < 4; ++j) inv[j] = 1.0f / lsum[j];

        if (pass == 0) {
            #pragma unroll
            for (int dt = 0; dt < 8; ++dt)
                #pragma unroll
                for (int j = 0; j < 4; ++j) z[dt][j] = o[dt][j] * inv[j];
        } else {
            #pragma unroll
            for (int dt = 0; dt < 8; ++dt)
                #pragma unroll
                for (int j = 0; j < 4; ++j) {
                    float d = z[dt][j] - o[dt][j] * inv[j];
                    sqacc += d * d;
                }
        }
        __syncthreads();
    }

    #pragma unroll
    for (int off = 1; off < 64; off <<= 1) sqacc += __shfl_xor(sqacc, off);
    if (lx == 0) red[w] = sqacc;
    __syncthreads();
    if (tid == 0) atomicAdd(out, (red[0] + red[1]) * (1.0f / 1048576.0f));
}

extern "C" void kernel_launch(void* const* d_in, const int* in_sizes, int n_in,
                              void* d_out, int out_size, void* d_ws, size_t ws_size,
                              hipStream_t stream) {
    const float* q  = (const float*)d_in[0];
    const float* k  = (const float*)d_in[1];
    const float* v  = (const float*)d_in[2];
    const float* ck = (const float*)d_in[3];
    const float* cv = (const float*)d_in[4];
    float* out = (float*)d_out;

    hipMemsetAsync(out, 0, sizeof(float), stream);

    if (ws_size >= WS_NEED) {
        char* ws = (char*)d_ws;
        convert_kv<<<dim3(NCHT + NCHC), dim3(256), 0, stream>>>(k, v, ck, cv, ws);
        attn_partial<<<dim3(256), dim3(512), 0, stream>>>(q, ws);
        combine_mse<<<dim3(256), dim3(256), 0, stream>>>(ws, out);
    } else {
        fused_attn_mse<<<dim3(256), dim3(128), 0, stream>>>(q, k, v, ck, cv, out);
    }
}